// Round 6
// baseline (324.447 us; speedup 1.0000x reference)
//
#include <hip/hip_runtime.h>
#include <math.h>

#define N_NODES 100000
#define N_EDGES 1600000

static inline size_t align256(size_t x) { return (x + 255) & ~((size_t)255); }

constexpr int SCAN_T = 1024;
constexpr int NCHUNK = (N_NODES + SCAN_T - 1) / SCAN_T;  // 98

typedef _Float16 h2 __attribute__((ext_vector_type(2)));
union HU { float f; unsigned u; h2 h; };

#if __has_builtin(__builtin_amdgcn_fdot2)
__device__ inline float fdot2f(h2 a, h2 b, float c) {
  return __builtin_amdgcn_fdot2(a, b, c, false);
}
#else
__device__ inline float fdot2f(h2 a, h2 b, float c) {
  return c + (float)a.x * (float)b.x + (float)a.y * (float)b.y;
}
#endif

// ---------------- fused: x(f32)->h0(fp16) convert + pass1 histogram ----------------
// The returning atomics are the latency/throughput hog; the streaming convert
// gives co-resident waves real work while atomics retire.

__global__ void tohalf_pass1_kernel(const float* __restrict__ x, _Float16* __restrict__ h0,
                                    const int* __restrict__ dst, int* __restrict__ cnt,
                                    int* __restrict__ pos) {
  const int gtid = blockIdx.x * blockDim.x + threadIdx.x;
  const int nth = gridDim.x * blockDim.x;
  for (int i = gtid; i < N_EDGES / 4; i += nth) {
    int4 d = ((const int4*)dst)[i];
    int4 p;
    p.x = atomicAdd(&cnt[d.x], 1);
    p.y = atomicAdd(&cnt[d.y], 1);
    p.z = atomicAdd(&cnt[d.z], 1);
    p.w = atomicAdd(&cnt[d.w], 1);
    ((int4*)pos)[i] = p;
  }
  for (int i = gtid; i < N_NODES * 64 / 8; i += nth) {
    float4 a = ((const float4*)x)[2 * i];
    float4 b = ((const float4*)x)[2 * i + 1];
    HU p0, p1, p2, p3;
    p0.h.x = (_Float16)a.x; p0.h.y = (_Float16)a.y;
    p1.h.x = (_Float16)a.z; p1.h.y = (_Float16)a.w;
    p2.h.x = (_Float16)b.x; p2.h.y = (_Float16)b.y;
    p3.h.x = (_Float16)b.z; p3.h.y = (_Float16)b.w;
    ((uint4*)h0)[i] = make_uint4(p0.u, p1.u, p2.u, p3.u);
  }
}

// ---------------- scans ----------------

__global__ __launch_bounds__(1024) void scan1_kernel(const int* __restrict__ cnt,
                                                     int* __restrict__ rowptr,
                                                     int* __restrict__ blocksum,
                                                     float* __restrict__ invdeg) {
  __shared__ int s[SCAN_T];
  int t = threadIdx.x;
  int i = blockIdx.x * SCAN_T + t;
  int v = (i < N_NODES) ? cnt[i] : 0;
  s[t] = v;
  __syncthreads();
  for (int off = 1; off < SCAN_T; off <<= 1) {
    int add = (t >= off) ? s[t - off] : 0;
    __syncthreads();
    s[t] += add;
    __syncthreads();
  }
  if (i < N_NODES) {
    rowptr[i] = s[t] - v;  // exclusive (pre block offset)
    invdeg[i] = 1.0f / (float)((v > 0) ? v : 1);
  }
  if (t == SCAN_T - 1) blocksum[blockIdx.x] = s[t];
}

__global__ void scan2_kernel(int* __restrict__ blocksum, int nb) {
  __shared__ int s[128];
  int t = threadIdx.x;  // 128 threads
  int v = (t < nb) ? blocksum[t] : 0;
  s[t] = v;
  __syncthreads();
  for (int off = 1; off < 128; off <<= 1) {
    int add = (t >= off) ? s[t - off] : 0;
    __syncthreads();
    s[t] += add;
    __syncthreads();
  }
  if (t < nb) blocksum[t] = s[t] - v;  // exclusive block offsets
}

__global__ __launch_bounds__(1024) void scan3_kernel(int* __restrict__ rowptr,
                                                     const int* __restrict__ blocksum) {
  int i = blockIdx.x * SCAN_T + threadIdx.x;
  if (i < N_NODES) rowptr[i] += blocksum[blockIdx.x];
}

// ---------------- pass2: col scatter only (no atomics — positions known) ----------------

__global__ void pass2_kernel(const int* __restrict__ src, const int* __restrict__ dst,
                             const int* __restrict__ pos, const int* __restrict__ rowptr,
                             int* __restrict__ col) {
  int i = blockIdx.x * blockDim.x + threadIdx.x;
  if (i < N_EDGES / 4) {
    int4 s4 = ((const int4*)src)[i];
    int4 d4 = ((const int4*)dst)[i];
    int4 p4 = ((const int4*)pos)[i];
    col[rowptr[d4.x] + p4.x] = s4.x;
    col[rowptr[d4.y] + p4.y] = s4.y;
    col[rowptr[d4.z] + p4.z] = s4.z;
    col[rowptr[d4.w] + p4.w] = s4.w;
  }
}

// ---------------- fused SAGEConv + BN + ReLU (layers 0 and 1), fp16 h ----------------
// block = 512 = 8 waves; each wave does 8 nodes/round.
// DO_COEF (layer 0): each block first fires its slice of the 1.6M non-returning
//   coef[src] += invdeg[dst] atomics; they retire under the layer's LDS/VALU work.
// DO_SUMS (layer 1): accumulates sums[j]=Σ h[j], sums[64+j]=Σ coef[node]*h[j];
//   h2 never materialized.

template <bool WRITE_OUT, bool DO_SUMS, bool DO_COEF>
__global__ __launch_bounds__(512) void layer_kernel(
    const _Float16* __restrict__ hin, const int* __restrict__ rowptr,
    const int* __restrict__ cnt, const int* __restrict__ col,
    const float* __restrict__ wl, const float* __restrict__ bl,
    const float* __restrict__ wr,
    const float* __restrict__ g, const float* __restrict__ be,
    const float* __restrict__ m, const float* __restrict__ v,
    _Float16* __restrict__ hout, const float* __restrict__ coef,
    float* __restrict__ sums,
    const int* __restrict__ esrc, const int* __restrict__ edst,
    const float* __restrict__ invdeg, float* __restrict__ coefw) {
  __shared__ uint4 wwS[1024];        // [k4*64+j]: {wl01,wl23,wr01,wr23} fp16 pairs, 16 KB
  __shared__ uint4 exS[8][8][17];    // [wave][node][c-group(16)+pad]: {a01,a23,o01,o23}
  __shared__ float scaleS[64], shiftS[64], biasS[64];
  __shared__ float redS[8][128];

  const int tid = threadIdx.x;

  if (DO_COEF) {
    const int nth = gridDim.x * blockDim.x;
    for (int i = blockIdx.x * blockDim.x + tid; i < N_EDGES / 4; i += nth) {
      int4 s4 = ((const int4*)esrc)[i];
      int4 d4 = ((const int4*)edst)[i];
      atomicAdd(&coefw[s4.x], invdeg[d4.x]);
      atomicAdd(&coefw[s4.y], invdeg[d4.y]);
      atomicAdd(&coefw[s4.z], invdeg[d4.z]);
      atomicAdd(&coefw[s4.w], invdeg[d4.w]);
    }
  }

  for (int idx = tid; idx < 1024; idx += 512) {
    int k4 = idx >> 6, j = idx & 63;
    const float* pl = wl + j * 64 + k4 * 4;
    const float* pr = wr + j * 64 + k4 * 4;
    HU a0, a1, o0, o1;
    a0.h.x = (_Float16)pl[0]; a0.h.y = (_Float16)pl[1];
    a1.h.x = (_Float16)pl[2]; a1.h.y = (_Float16)pl[3];
    o0.h.x = (_Float16)pr[0]; o0.h.y = (_Float16)pr[1];
    o1.h.x = (_Float16)pr[2]; o1.h.y = (_Float16)pr[3];
    wwS[idx] = make_uint4(a0.u, a1.u, o0.u, o1.u);
  }
  if (tid < 64) {
    float sc = rsqrtf(v[tid] + 1e-5f) * g[tid];
    scaleS[tid] = sc;
    shiftS[tid] = be[tid] - m[tid] * sc;
    biasS[tid] = bl[tid];
  }
  __syncthreads();

  const int lane = tid & 63;
  const int wv = tid >> 6;
  const int slot = lane >> 4;   // 0..3 node slot
  const int c = lane & 15;      // channel quad (4 halfs = 8 B)
  const int wid = blockIdx.x * 8 + wv;
  const int nwaves = gridDim.x * 8;
  float accsum = 0.0f, accsum2 = 0.0f;

  for (int gidx = wid; gidx < (N_NODES / 8); gidx += nwaves) {
    const int nbase = gidx * 8;

    // ---- phase 1: gather 8 nodes (fp16) ----
#pragma unroll
    for (int sub = 0; sub < 2; ++sub) {
      const int node = nbase + sub * 4 + slot;
      const float2 ownraw = ((const float2*)(hin + (size_t)node * 64))[c];
      const int start = rowptr[node];
      const int deg = cnt[node];
      const int* cp = col + start;
      h2 a01 = (h2)(_Float16)0, a23 = (h2)(_Float16)0;
      int e = 0;
      for (; e + 4 <= deg; e += 4) {
        int s0 = cp[e], s1 = cp[e + 1], s2 = cp[e + 2], s3 = cp[e + 3];
        float2 r0 = ((const float2*)(hin + (size_t)s0 * 64))[c];
        float2 r1 = ((const float2*)(hin + (size_t)s1 * 64))[c];
        float2 r2 = ((const float2*)(hin + (size_t)s2 * 64))[c];
        float2 r3 = ((const float2*)(hin + (size_t)s3 * 64))[c];
        HU u;
        u.f = r0.x; a01 += u.h; u.f = r0.y; a23 += u.h;
        u.f = r1.x; a01 += u.h; u.f = r1.y; a23 += u.h;
        u.f = r2.x; a01 += u.h; u.f = r2.y; a23 += u.h;
        u.f = r3.x; a01 += u.h; u.f = r3.y; a23 += u.h;
      }
      for (; e < deg; ++e) {
        float2 r0 = ((const float2*)(hin + (size_t)cp[e] * 64))[c];
        HU u;
        u.f = r0.x; a01 += u.h; u.f = r0.y; a23 += u.h;
      }
      const _Float16 hinv = (_Float16)((deg > 0) ? (1.0f / (float)deg) : 0.0f);
      h2 vinv; vinv.x = hinv; vinv.y = hinv;
      a01 *= vinv; a23 *= vinv;
      HU wa0, wa1, wo0, wo1;
      wa0.h = a01; wa1.h = a23;
      wo0.f = ownraw.x; wo1.f = ownraw.y;
      exS[wv][sub * 4 + slot][c] = make_uint4(wa0.u, wa1.u, wo0.u, wo1.u);
    }
    // same-wave produce/consume; compiler inserts lgkmcnt waits — no barrier

    // ---- phase 2: transform, lane = output channel j ----
    float out[8] = {0.f, 0.f, 0.f, 0.f, 0.f, 0.f, 0.f, 0.f};
#pragma unroll 4
    for (int k4 = 0; k4 < 16; ++k4) {
      uint4 w4 = wwS[k4 * 64 + lane];
      HU wl01, wl23, wr01, wr23;
      wl01.u = w4.x; wl23.u = w4.y; wr01.u = w4.z; wr23.u = w4.w;
#pragma unroll
      for (int n = 0; n < 8; ++n) {
        uint4 ao = exS[wv][n][k4];
        HU a01, a23, o01, o23;
        a01.u = ao.x; a23.u = ao.y; o01.u = ao.z; o23.u = ao.w;
        float t = out[n];
        t = fdot2f(a01.h, wl01.h, t);
        t = fdot2f(a23.h, wl23.h, t);
        t = fdot2f(o01.h, wr01.h, t);
        t = fdot2f(o23.h, wr23.h, t);
        out[n] = t;
      }
    }

    const float sc = scaleS[lane], sh = shiftS[lane], bi = biasS[lane];
#pragma unroll
    for (int n = 0; n < 8; ++n) {
      float o = fmaxf((out[n] + bi) * sc + sh, 0.0f);
      if (DO_SUMS) {
        accsum += o;
        accsum2 += coef[nbase + n] * o;
      }
      if (WRITE_OUT) hout[(size_t)(nbase + n) * 64 + lane] = (_Float16)o;
    }
  }

  if (DO_SUMS) {
    redS[wv][lane] = accsum;
    redS[wv][64 + lane] = accsum2;
    __syncthreads();
    if (wv == 0) {
      float t0 = 0.f, t1 = 0.f;
#pragma unroll
      for (int w = 0; w < 8; ++w) {
        t0 += redS[w][lane];
        t1 += redS[w][64 + lane];
      }
      atomicAdd(&sums[lane], t0);
      atomicAdd(&sums[64 + lane], t1);
    }
  }
}

// ---------------- collapsed layer 2 + classifier + sigmoid ----------------

__global__ void final_kernel(const float* __restrict__ sums,
                             const float* __restrict__ wl2, const float* __restrict__ bl2,
                             const float* __restrict__ wr2,
                             const float* __restrict__ cw1, const float* __restrict__ cb1,
                             const float* __restrict__ cw2, const float* __restrict__ cb2,
                             float* __restrict__ out) {
  __shared__ float maS[64], mhS[64], m3S[64], tS[64];
  int j = threadIdx.x;  // 64 threads
  float invN = 1.0f / (float)N_NODES;
  mhS[j] = sums[j] * invN;        // mean of h2
  maS[j] = sums[64 + j] * invN;   // mean of aggr3
  __syncthreads();
  float acc = bl2[j];
#pragma unroll
  for (int k = 0; k < 64; ++k)
    acc += wl2[j * 64 + k] * maS[k] + wr2[j * 64 + k] * mhS[k];
  m3S[j] = acc;
  __syncthreads();
  float c = cb1[j];
#pragma unroll
  for (int k = 0; k < 64; ++k) c += cw1[j * 64 + k] * m3S[k];
  tS[j] = fmaxf(c, 0.f);
  __syncthreads();
  float r = tS[j] * cw2[j];
#pragma unroll
  for (int off = 32; off > 0; off >>= 1) r += __shfl_down(r, off);
  if (j == 0) out[0] = 1.0f / (1.0f + expf(-(r + cb2[0])));
}

// ---------------- host launcher ----------------

extern "C" void kernel_launch(void* const* d_in, const int* in_sizes, int n_in,
                              void* d_out, int out_size, void* d_ws, size_t ws_size,
                              hipStream_t stream) {
  const float* x   = (const float*)d_in[0];
  const int* ei    = (const int*)d_in[1];
  const float* wl0 = (const float*)d_in[2];
  const float* bl0 = (const float*)d_in[3];
  const float* wr0 = (const float*)d_in[4];
  const float* wl1 = (const float*)d_in[5];
  const float* bl1 = (const float*)d_in[6];
  const float* wr1 = (const float*)d_in[7];
  const float* wl2 = (const float*)d_in[8];
  const float* bl2 = (const float*)d_in[9];
  const float* wr2 = (const float*)d_in[10];
  const float* g0  = (const float*)d_in[11];
  const float* be0 = (const float*)d_in[12];
  const float* m0  = (const float*)d_in[13];
  const float* v0  = (const float*)d_in[14];
  const float* g1  = (const float*)d_in[15];
  const float* be1 = (const float*)d_in[16];
  const float* m1  = (const float*)d_in[17];
  const float* v1  = (const float*)d_in[18];
  const float* cw1 = (const float*)d_in[19];
  const float* cb1 = (const float*)d_in[20];
  const float* cw2 = (const float*)d_in[21];
  const float* cb2 = (const float*)d_in[22];

  const int* srcp = ei;            // edge_index[0]
  const int* dstp = ei + N_EDGES;  // edge_index[1]

  char* ws = (char*)d_ws;
  size_t off = 0;
  auto alloc = [&](size_t bytes) {
    void* p = ws + off;
    off = align256(off + bytes);
    return p;
  };
  int* cnt        = (int*)alloc((size_t)N_NODES * 4);
  int* rowptr     = (int*)alloc((size_t)N_NODES * 4);
  float* invdeg   = (float*)alloc((size_t)N_NODES * 4);
  float* coef     = (float*)alloc((size_t)N_NODES * 4);
  int* blocksum   = (int*)alloc(128 * 4);
  int* pos        = (int*)alloc((size_t)N_EDGES * 4);
  int* col        = (int*)alloc((size_t)N_EDGES * 4);
  float* sums     = (float*)alloc(128 * 4);
  _Float16* h0    = (_Float16*)alloc((size_t)N_NODES * 64 * 2);
  _Float16* h1    = (_Float16*)alloc((size_t)N_NODES * 64 * 2);
  (void)off; (void)ws_size; (void)in_sizes; (void)n_in; (void)out_size;

  hipMemsetAsync(cnt, 0, (size_t)N_NODES * 4, stream);
  hipMemsetAsync(coef, 0, (size_t)N_NODES * 4, stream);
  hipMemsetAsync(sums, 0, 128 * 4, stream);

  tohalf_pass1_kernel<<<1024, 256, 0, stream>>>(x, h0, dstp, cnt, pos);
  scan1_kernel<<<NCHUNK, SCAN_T, 0, stream>>>(cnt, rowptr, blocksum, invdeg);
  scan2_kernel<<<1, 128, 0, stream>>>(blocksum, NCHUNK);
  scan3_kernel<<<NCHUNK, SCAN_T, 0, stream>>>(rowptr, blocksum);
  int eg4 = (N_EDGES / 4 + 255) / 256;
  pass2_kernel<<<eg4, 256, 0, stream>>>(srcp, dstp, pos, rowptr, col);

  layer_kernel<true, false, true><<<768, 512, 0, stream>>>(
      h0, rowptr, cnt, col, wl0, bl0, wr0, g0, be0, m0, v0, h1, nullptr, nullptr,
      srcp, dstp, invdeg, coef);
  layer_kernel<false, true, false><<<768, 512, 0, stream>>>(
      h1, rowptr, cnt, col, wl1, bl1, wr1, g1, be1, m1, v1, nullptr, coef, sums,
      nullptr, nullptr, nullptr, nullptr);
  final_kernel<<<1, 64, 0, stream>>>(sums, wl2, bl2, wr2, cw1, cb1, cw2, cb2,
                                     (float*)d_out);
}

// Round 7
// 305.109 us; speedup vs baseline: 1.0634x; 1.0634x over previous
//
#include <hip/hip_runtime.h>
#include <math.h>

#define N_NODES 100000
#define N_EDGES 1600000

static inline size_t align256(size_t x) { return (x + 255) & ~((size_t)255); }

constexpr int NB = (N_NODES + 255) / 256;  // 391 buckets (dst>>8)
constexpr int CAP = 6144;                  // bucket capacity (avg ~4092, huge margin)
constexpr int LAYER_BLOCKS = 768;
constexpr int COEF_BLOCKS = 128;

typedef _Float16 h2 __attribute__((ext_vector_type(2)));
union HU { float f; unsigned u; h2 h; };

#if __has_builtin(__builtin_amdgcn_fdot2)
__device__ inline float fdot2f(h2 a, h2 b, float c) {
  return __builtin_amdgcn_fdot2(a, b, c, false);
}
#else
__device__ inline float fdot2f(h2 a, h2 b, float c) {
  return c + (float)a.x * (float)b.x + (float)a.y * (float)b.y;
}
#endif

// ---------------- K1: bucket-append by dst>>8, fused with x->fp16 convert ----------------
// Atomic counters padded to one per 64B line (391 hot lines, parallel across L2
// channels); pair appends are dense within bucket regions -> coalesce in L2.

__global__ void bucket_kernel(const float* __restrict__ x, _Float16* __restrict__ h0,
                              const int* __restrict__ src, const int* __restrict__ dst,
                              int* __restrict__ bfill, int2* __restrict__ pairs) {
  const int gtid = blockIdx.x * blockDim.x + threadIdx.x;
  const int nth = gridDim.x * blockDim.x;
  for (int i = gtid; i < N_EDGES / 4; i += nth) {
    int4 s4 = ((const int4*)src)[i];
    int4 d4 = ((const int4*)dst)[i];
#define PUT(S, D)                                         \
    {                                                     \
      int b = (D) >> 8;                                   \
      int p = atomicAdd(&bfill[b * 16], 1);               \
      pairs[(size_t)b * CAP + p] = make_int2((S), (D));   \
    }
    PUT(s4.x, d4.x) PUT(s4.y, d4.y) PUT(s4.z, d4.z) PUT(s4.w, d4.w)
#undef PUT
  }
  for (int i = gtid; i < N_NODES * 64 / 8; i += nth) {
    float4 a = ((const float4*)x)[2 * i];
    float4 b = ((const float4*)x)[2 * i + 1];
    HU p0, p1, p2, p3;
    p0.h.x = (_Float16)a.x; p0.h.y = (_Float16)a.y;
    p1.h.x = (_Float16)a.z; p1.h.y = (_Float16)a.w;
    p2.h.x = (_Float16)b.x; p2.h.y = (_Float16)b.y;
    p3.h.x = (_Float16)b.z; p3.h.y = (_Float16)b.w;
    ((uint4*)h0)[i] = make_uint4(p0.u, p1.u, p2.u, p3.u);
  }
}

// ---------------- K2: exclusive scan of 391 bucket counts (single block) ----------------

__global__ __launch_bounds__(512) void bscan_kernel(const int* __restrict__ bfill,
                                                    int* __restrict__ bbase) {
  __shared__ int s[512];
  int t = threadIdx.x;
  int v = (t < NB) ? bfill[t * 16] : 0;
  s[t] = v;
  __syncthreads();
  for (int off = 1; off < 512; off <<= 1) {
    int a = (t >= off) ? s[t - off] : 0;
    __syncthreads();
    s[t] += a;
    __syncthreads();
  }
  if (t < NB) bbase[t] = s[t] - v;  // exclusive
}

// ---------------- K3: per-bucket LDS counting sort -> col, rowptr, cnt, invdeg ----------------
// One block per bucket (~4092 edges, 256 distinct dst). All global writes coalesced
// or L2-dense. Within-row col order is arbitrary (sum is commutative).

__global__ __launch_bounds__(256) void csr_kernel(const int2* __restrict__ pairs,
                                                  const int* __restrict__ bfill,
                                                  const int* __restrict__ bbase,
                                                  int* __restrict__ col,
                                                  int* __restrict__ rowptr,
                                                  int* __restrict__ cnt,
                                                  float* __restrict__ invdeg) {
  __shared__ int hist[256], sc[256], offs[256];
  const int b = blockIdx.x;
  const int t = threadIdx.x;
  hist[t] = 0;
  __syncthreads();
  const int count = bfill[b * 16];
  const int base = bbase[b];
  const int2* bp = pairs + (size_t)b * CAP;
  for (int i = t; i < count; i += 256) atomicAdd(&hist[bp[i].y & 255], 1);
  __syncthreads();
  int v = hist[t];
  sc[t] = v;
  __syncthreads();
  for (int off = 1; off < 256; off <<= 1) {
    int a = (t >= off) ? sc[t - off] : 0;
    __syncthreads();
    sc[t] += a;
    __syncthreads();
  }
  const int excl = sc[t] - v;
  offs[t] = base + excl;
  const int node = b * 256 + t;
  if (node < N_NODES) {
    rowptr[node] = base + excl;
    cnt[node] = v;
    invdeg[node] = 1.0f / (float)((v > 0) ? v : 1);
  }
  __syncthreads();
  for (int i = t; i < count; i += 256) {
    int2 e = bp[i];
    int p = atomicAdd(&offs[e.y & 255], 1);
    col[p] = e.x;
  }
}

// ---------------- fused SAGEConv + BN + ReLU (layers 0 and 1), fp16 h ----------------
// block = 512 = 8 waves; each wave does 8 nodes per round.
// DO_COEF (layer 0): blocks >= LAYER_BLOCKS do ONLY the coef atomic stream
//   (coef[src] += invdeg[dst], reading dst-sorted pairs so invdeg loads are L1
//   hits) -- running on separate CUs concurrently with the layer compute.
// DO_SUMS (layer 1): accumulates sums[j]=sum h[j], sums[64+j]=sum coef[n]*h[j].

template <bool WRITE_OUT, bool DO_SUMS, bool DO_COEF>
__global__ __launch_bounds__(512) void layer_kernel(
    const _Float16* __restrict__ hin, const int* __restrict__ rowptr,
    const int* __restrict__ cnt, const int* __restrict__ col,
    const float* __restrict__ wl, const float* __restrict__ bl,
    const float* __restrict__ wr,
    const float* __restrict__ g, const float* __restrict__ be,
    const float* __restrict__ m, const float* __restrict__ v,
    _Float16* __restrict__ hout, const float* __restrict__ coef,
    float* __restrict__ sums,
    const int2* __restrict__ pairs, const int* __restrict__ bfill,
    const float* __restrict__ invdeg, float* __restrict__ coefw) {
  __shared__ uint4 wwS[1024];        // [k4*64+j]: {wl01,wl23,wr01,wr23} fp16 pairs, 16 KB
  __shared__ uint4 exS[8][8][17];    // [wave][node][c-group(16)+pad]
  __shared__ float scaleS[64], shiftS[64], biasS[64];
  __shared__ float redS[8][128];

  const int tid = threadIdx.x;

  if (DO_COEF && blockIdx.x >= LAYER_BLOCKS) {
    const int cb = blockIdx.x - LAYER_BLOCKS;
    for (int b = cb; b < NB; b += COEF_BLOCKS) {
      const int count = bfill[b * 16];
      const int2* bp = pairs + (size_t)b * CAP;
      for (int i = tid; i < count; i += 512) {
        int2 e = bp[i];
        atomicAdd(&coefw[e.x], invdeg[e.y]);
      }
    }
    return;
  }

  for (int idx = tid; idx < 1024; idx += 512) {
    int k4 = idx >> 6, j = idx & 63;
    const float* pl = wl + j * 64 + k4 * 4;
    const float* pr = wr + j * 64 + k4 * 4;
    HU a0, a1, o0, o1;
    a0.h.x = (_Float16)pl[0]; a0.h.y = (_Float16)pl[1];
    a1.h.x = (_Float16)pl[2]; a1.h.y = (_Float16)pl[3];
    o0.h.x = (_Float16)pr[0]; o0.h.y = (_Float16)pr[1];
    o1.h.x = (_Float16)pr[2]; o1.h.y = (_Float16)pr[3];
    wwS[idx] = make_uint4(a0.u, a1.u, o0.u, o1.u);
  }
  if (tid < 64) {
    float sc = rsqrtf(v[tid] + 1e-5f) * g[tid];
    scaleS[tid] = sc;
    shiftS[tid] = be[tid] - m[tid] * sc;
    biasS[tid] = bl[tid];
  }
  __syncthreads();

  const int lane = tid & 63;
  const int wv = tid >> 6;
  const int slot = lane >> 4;   // 0..3 node slot
  const int c = lane & 15;      // channel quad (4 halfs = 8 B)
  const int wid = blockIdx.x * 8 + wv;
  const int nwaves = (DO_COEF ? LAYER_BLOCKS : gridDim.x) * 8;
  float accsum = 0.0f, accsum2 = 0.0f;

  for (int gidx = wid; gidx < (N_NODES / 8); gidx += nwaves) {
    const int nbase = gidx * 8;

    // ---- phase 1: gather 8 nodes (fp16) ----
#pragma unroll
    for (int sub = 0; sub < 2; ++sub) {
      const int node = nbase + sub * 4 + slot;
      const float2 ownraw = ((const float2*)(hin + (size_t)node * 64))[c];
      const int start = rowptr[node];
      const int deg = cnt[node];
      const int* cp = col + start;
      h2 a01 = (h2)(_Float16)0, a23 = (h2)(_Float16)0;
      int e = 0;
      for (; e + 4 <= deg; e += 4) {
        int s0 = cp[e], s1 = cp[e + 1], s2 = cp[e + 2], s3 = cp[e + 3];
        float2 r0 = ((const float2*)(hin + (size_t)s0 * 64))[c];
        float2 r1 = ((const float2*)(hin + (size_t)s1 * 64))[c];
        float2 r2 = ((const float2*)(hin + (size_t)s2 * 64))[c];
        float2 r3 = ((const float2*)(hin + (size_t)s3 * 64))[c];
        HU u;
        u.f = r0.x; a01 += u.h; u.f = r0.y; a23 += u.h;
        u.f = r1.x; a01 += u.h; u.f = r1.y; a23 += u.h;
        u.f = r2.x; a01 += u.h; u.f = r2.y; a23 += u.h;
        u.f = r3.x; a01 += u.h; u.f = r3.y; a23 += u.h;
      }
      for (; e < deg; ++e) {
        float2 r0 = ((const float2*)(hin + (size_t)cp[e] * 64))[c];
        HU u;
        u.f = r0.x; a01 += u.h; u.f = r0.y; a23 += u.h;
      }
      const _Float16 hinv = (_Float16)((deg > 0) ? (1.0f / (float)deg) : 0.0f);
      h2 vinv; vinv.x = hinv; vinv.y = hinv;
      a01 *= vinv; a23 *= vinv;
      HU wa0, wa1, wo0, wo1;
      wa0.h = a01; wa1.h = a23;
      wo0.f = ownraw.x; wo1.f = ownraw.y;
      exS[wv][sub * 4 + slot][c] = make_uint4(wa0.u, wa1.u, wo0.u, wo1.u);
    }
    // same-wave produce/consume; compiler inserts lgkmcnt waits -- no barrier

    // ---- phase 2: transform, lane = output channel j ----
    float out[8] = {0.f, 0.f, 0.f, 0.f, 0.f, 0.f, 0.f, 0.f};
#pragma unroll 4
    for (int k4 = 0; k4 < 16; ++k4) {
      uint4 w4 = wwS[k4 * 64 + lane];
      HU wl01, wl23, wr01, wr23;
      wl01.u = w4.x; wl23.u = w4.y; wr01.u = w4.z; wr23.u = w4.w;
#pragma unroll
      for (int n = 0; n < 8; ++n) {
        uint4 ao = exS[wv][n][k4];
        HU a01, a23, o01, o23;
        a01.u = ao.x; a23.u = ao.y; o01.u = ao.z; o23.u = ao.w;
        float t = out[n];
        t = fdot2f(a01.h, wl01.h, t);
        t = fdot2f(a23.h, wl23.h, t);
        t = fdot2f(o01.h, wr01.h, t);
        t = fdot2f(o23.h, wr23.h, t);
        out[n] = t;
      }
    }

    const float sc = scaleS[lane], sh = shiftS[lane], bi = biasS[lane];
#pragma unroll
    for (int n = 0; n < 8; ++n) {
      float o = fmaxf((out[n] + bi) * sc + sh, 0.0f);
      if (DO_SUMS) {
        accsum += o;
        accsum2 += coef[nbase + n] * o;
      }
      if (WRITE_OUT) hout[(size_t)(nbase + n) * 64 + lane] = (_Float16)o;
    }
  }

  if (DO_SUMS) {
    redS[wv][lane] = accsum;
    redS[wv][64 + lane] = accsum2;
    __syncthreads();
    if (wv == 0) {
      float t0 = 0.f, t1 = 0.f;
#pragma unroll
      for (int w = 0; w < 8; ++w) {
        t0 += redS[w][lane];
        t1 += redS[w][64 + lane];
      }
      atomicAdd(&sums[lane], t0);
      atomicAdd(&sums[64 + lane], t1);
    }
  }
}

// ---------------- collapsed layer 2 + classifier + sigmoid ----------------

__global__ void final_kernel(const float* __restrict__ sums,
                             const float* __restrict__ wl2, const float* __restrict__ bl2,
                             const float* __restrict__ wr2,
                             const float* __restrict__ cw1, const float* __restrict__ cb1,
                             const float* __restrict__ cw2, const float* __restrict__ cb2,
                             float* __restrict__ out) {
  __shared__ float maS[64], mhS[64], m3S[64], tS[64];
  int j = threadIdx.x;  // 64 threads
  float invN = 1.0f / (float)N_NODES;
  mhS[j] = sums[j] * invN;        // mean of h2
  maS[j] = sums[64 + j] * invN;   // mean of aggr3
  __syncthreads();
  float acc = bl2[j];
#pragma unroll
  for (int k = 0; k < 64; ++k)
    acc += wl2[j * 64 + k] * maS[k] + wr2[j * 64 + k] * mhS[k];
  m3S[j] = acc;
  __syncthreads();
  float c = cb1[j];
#pragma unroll
  for (int k = 0; k < 64; ++k) c += cw1[j * 64 + k] * m3S[k];
  tS[j] = fmaxf(c, 0.f);
  __syncthreads();
  float r = tS[j] * cw2[j];
#pragma unroll
  for (int off = 32; off > 0; off >>= 1) r += __shfl_down(r, off);
  if (j == 0) out[0] = 1.0f / (1.0f + expf(-(r + cb2[0])));
}

// ---------------- host launcher ----------------

extern "C" void kernel_launch(void* const* d_in, const int* in_sizes, int n_in,
                              void* d_out, int out_size, void* d_ws, size_t ws_size,
                              hipStream_t stream) {
  const float* x   = (const float*)d_in[0];
  const int* ei    = (const int*)d_in[1];
  const float* wl0 = (const float*)d_in[2];
  const float* bl0 = (const float*)d_in[3];
  const float* wr0 = (const float*)d_in[4];
  const float* wl1 = (const float*)d_in[5];
  const float* bl1 = (const float*)d_in[6];
  const float* wr1 = (const float*)d_in[7];
  const float* wl2 = (const float*)d_in[8];
  const float* bl2 = (const float*)d_in[9];
  const float* wr2 = (const float*)d_in[10];
  const float* g0  = (const float*)d_in[11];
  const float* be0 = (const float*)d_in[12];
  const float* m0  = (const float*)d_in[13];
  const float* v0  = (const float*)d_in[14];
  const float* g1  = (const float*)d_in[15];
  const float* be1 = (const float*)d_in[16];
  const float* m1  = (const float*)d_in[17];
  const float* v1  = (const float*)d_in[18];
  const float* cw1 = (const float*)d_in[19];
  const float* cb1 = (const float*)d_in[20];
  const float* cw2 = (const float*)d_in[21];
  const float* cb2 = (const float*)d_in[22];

  const int* srcp = ei;            // edge_index[0]
  const int* dstp = ei + N_EDGES;  // edge_index[1]

  char* ws = (char*)d_ws;
  size_t off = 0;
  auto alloc = [&](size_t bytes) {
    void* p = ws + off;
    off = align256(off + bytes);
    return p;
  };
  int* bfill      = (int*)alloc((size_t)512 * 16 * 4);   // padded counters (64B apart)
  int* bbase      = (int*)alloc((size_t)512 * 4);
  int2* pairs     = (int2*)alloc((size_t)NB * CAP * 8);  // ~19.2 MB
  int* rowptr     = (int*)alloc((size_t)N_NODES * 4);
  int* cnt        = (int*)alloc((size_t)N_NODES * 4);
  float* invdeg   = (float*)alloc((size_t)N_NODES * 4);
  float* coef     = (float*)alloc((size_t)N_NODES * 4);
  int* col        = (int*)alloc((size_t)N_EDGES * 4);
  float* sums     = (float*)alloc(128 * 4);
  _Float16* h0    = (_Float16*)alloc((size_t)N_NODES * 64 * 2);
  _Float16* h1    = (_Float16*)alloc((size_t)N_NODES * 64 * 2);
  (void)off; (void)ws_size; (void)in_sizes; (void)n_in; (void)out_size;

  hipMemsetAsync(bfill, 0, (size_t)512 * 16 * 4, stream);
  hipMemsetAsync(coef, 0, (size_t)N_NODES * 4, stream);
  hipMemsetAsync(sums, 0, 128 * 4, stream);

  bucket_kernel<<<1024, 256, 0, stream>>>(x, h0, srcp, dstp, bfill, pairs);
  bscan_kernel<<<1, 512, 0, stream>>>(bfill, bbase);
  csr_kernel<<<NB, 256, 0, stream>>>(pairs, bfill, bbase, col, rowptr, cnt, invdeg);

  layer_kernel<true, false, true><<<LAYER_BLOCKS + COEF_BLOCKS, 512, 0, stream>>>(
      h0, rowptr, cnt, col, wl0, bl0, wr0, g0, be0, m0, v0, h1, nullptr, nullptr,
      pairs, bfill, invdeg, coef);
  layer_kernel<false, true, false><<<LAYER_BLOCKS, 512, 0, stream>>>(
      h1, rowptr, cnt, col, wl1, bl1, wr1, g1, be1, m1, v1, nullptr, coef, sums,
      nullptr, nullptr, nullptr, nullptr);
  final_kernel<<<1, 64, 0, stream>>>(sums, wl2, bl2, wr2, cw1, cb1, cw2, cb2,
                                     (float*)d_out);
}

// Round 8
// 247.176 us; speedup vs baseline: 1.3126x; 1.2344x over previous
//
#include <hip/hip_runtime.h>
#include <math.h>

#define N_NODES 100000
#define N_EDGES 1600000

static inline size_t align256(size_t x) { return (x + 255) & ~((size_t)255); }

constexpr int NB = (N_NODES + 255) / 256;      // 391 buckets (node>>8)
constexpr int CAP = 5120;                      // bucket capacity (avg 4092, max ~4350)
constexpr int NBLK_PART = 512;
constexpr int CHUNK = (N_EDGES + NBLK_PART - 1) / NBLK_PART;  // 3125

typedef _Float16 h2 __attribute__((ext_vector_type(2)));
union HU { float f; unsigned u; h2 h; };

#if __has_builtin(__builtin_amdgcn_fdot2)
__device__ inline float fdot2f(h2 a, h2 b, float c) {
  return __builtin_amdgcn_fdot2(a, b, c, false);
}
#else
__device__ inline float fdot2f(h2 a, h2 b, float c) {
  return c + (float)a.x * (float)b.x + (float)a.y * (float)b.y;
}
#endif

// ---------------- K1: dual radix-partition (by dst>>8 and src>>8) + x->fp16 ----------------
// Per-block LDS histograms; only 2*391 returning global atomics per block to
// reserve dense per-bucket regions; pair writes are exact (no pos array, no
// per-edge global atomics).

__global__ __launch_bounds__(256) void partition_kernel(
    const float* __restrict__ x, _Float16* __restrict__ h0,
    const int* __restrict__ src, const int* __restrict__ dst,
    int* __restrict__ gfillD, int* __restrict__ gfillS,
    int2* __restrict__ pairsD, int2* __restrict__ pairsS) {
  __shared__ int histD[NB], histS[NB], offD[NB], offS[NB];
  const int blk = blockIdx.x;
  const int t = threadIdx.x;
  for (int i = t; i < NB; i += 256) { histD[i] = 0; histS[i] = 0; }
  __syncthreads();
  const int e0 = blk * CHUNK;
  const int e1 = (e0 + CHUNK < N_EDGES) ? (e0 + CHUNK) : N_EDGES;
  for (int e = e0 + t; e < e1; e += 256) {
    int s = src[e], d = dst[e];
    atomicAdd(&histD[d >> 8], 1);
    atomicAdd(&histS[s >> 8], 1);
  }
  __syncthreads();
  for (int i = t; i < NB; i += 256) {
    offD[i] = atomicAdd(&gfillD[i * 16], histD[i]);
    offS[i] = atomicAdd(&gfillS[i * 16], histS[i]);
  }
  __syncthreads();
  for (int e = e0 + t; e < e1; e += 256) {
    int s = src[e], d = dst[e];
    int bd = d >> 8;
    int rd = atomicAdd(&offD[bd], 1);
    pairsD[(size_t)bd * CAP + rd] = make_int2(s, d);
    int bs = s >> 8;
    int rs = atomicAdd(&offS[bs], 1);
    pairsS[(size_t)bs * CAP + rs] = make_int2(s, d);
  }
  // fused x -> fp16 convert (grid-stride over whole grid)
  const int gtid = blk * 256 + t;
  const int nth = gridDim.x * 256;
  for (int i = gtid; i < N_NODES * 64 / 8; i += nth) {
    float4 a = ((const float4*)x)[2 * i];
    float4 b = ((const float4*)x)[2 * i + 1];
    HU p0, p1, p2, p3;
    p0.h.x = (_Float16)a.x; p0.h.y = (_Float16)a.y;
    p1.h.x = (_Float16)a.z; p1.h.y = (_Float16)a.w;
    p2.h.x = (_Float16)b.x; p2.h.y = (_Float16)b.y;
    p3.h.x = (_Float16)b.z; p3.h.y = (_Float16)b.w;
    ((uint4*)h0)[i] = make_uint4(p0.u, p1.u, p2.u, p3.u);
  }
}

// ---------------- K2: exclusive scan of 391 dst-bucket counts (single block) ----------------

__global__ __launch_bounds__(512) void bscan_kernel(const int* __restrict__ bfill,
                                                    int* __restrict__ bbase) {
  __shared__ int s[512];
  int t = threadIdx.x;
  int v = (t < NB) ? bfill[t * 16] : 0;
  s[t] = v;
  __syncthreads();
  for (int off = 1; off < 512; off <<= 1) {
    int a = (t >= off) ? s[t - off] : 0;
    __syncthreads();
    s[t] += a;
    __syncthreads();
  }
  if (t < NB) bbase[t] = s[t] - v;  // exclusive
}

// ---------------- K3: per-dst-bucket LDS counting sort -> col, rowptr, cnt, invdeg ----------------

__global__ __launch_bounds__(256) void csr_kernel(const int2* __restrict__ pairs,
                                                  const int* __restrict__ bfill,
                                                  const int* __restrict__ bbase,
                                                  int* __restrict__ col,
                                                  int* __restrict__ rowptr,
                                                  int* __restrict__ cnt,
                                                  float* __restrict__ invdeg) {
  __shared__ int hist[256], sc[256], offs[256];
  const int b = blockIdx.x;
  const int t = threadIdx.x;
  hist[t] = 0;
  __syncthreads();
  const int count = bfill[b * 16];
  const int base = bbase[b];
  const int2* bp = pairs + (size_t)b * CAP;
  for (int i = t; i < count; i += 256) atomicAdd(&hist[bp[i].y & 255], 1);
  __syncthreads();
  int v = hist[t];
  sc[t] = v;
  __syncthreads();
  for (int off = 1; off < 256; off <<= 1) {
    int a = (t >= off) ? sc[t - off] : 0;
    __syncthreads();
    sc[t] += a;
    __syncthreads();
  }
  const int excl = sc[t] - v;
  offs[t] = base + excl;
  const int node = b * 256 + t;
  if (node < N_NODES) {
    rowptr[node] = base + excl;
    cnt[node] = v;
    invdeg[node] = 1.0f / (float)((v > 0) ? v : 1);
  }
  __syncthreads();
  for (int i = t; i < count; i += 256) {
    int2 e = bp[i];
    int p = atomicAdd(&offs[e.y & 255], 1);
    col[p] = e.x;
  }
}

// ---------------- K4: coef via per-src-bucket LDS accumulation (no global atomics) ----------------
// coef[s] = sum over out-edges of invdeg[dst]; invdeg is 400KB -> L2-resident reads.

__global__ __launch_bounds__(256) void coef_kernel(const int2* __restrict__ pairsS,
                                                   const int* __restrict__ gfillS,
                                                   const float* __restrict__ invdeg,
                                                   float* __restrict__ coef) {
  __shared__ float cl[256];
  const int b = blockIdx.x;
  const int t = threadIdx.x;
  cl[t] = 0.0f;
  __syncthreads();
  const int count = gfillS[b * 16];
  const int2* bp = pairsS + (size_t)b * CAP;
  for (int i = t; i < count; i += 256) {
    int2 e = bp[i];
    atomicAdd(&cl[e.x & 255], invdeg[e.y]);
  }
  __syncthreads();
  const int node = b * 256 + t;
  if (node < N_NODES) coef[node] = cl[t];
}

// ---------------- fused SAGEConv + BN + ReLU (layers 0 and 1), fp16 h ----------------
// block = 512 = 8 waves; each wave does 8 nodes per round.
// DO_SUMS (layer 1): accumulates sums[j]=sum h[j], sums[64+j]=sum coef[n]*h[j];
//   h2 never materialized (collapsed layer 2 + node-mean).

template <bool WRITE_OUT, bool DO_SUMS>
__global__ __launch_bounds__(512) void layer_kernel(
    const _Float16* __restrict__ hin, const int* __restrict__ rowptr,
    const int* __restrict__ cnt, const int* __restrict__ col,
    const float* __restrict__ wl, const float* __restrict__ bl,
    const float* __restrict__ wr,
    const float* __restrict__ g, const float* __restrict__ be,
    const float* __restrict__ m, const float* __restrict__ v,
    _Float16* __restrict__ hout, const float* __restrict__ coef,
    float* __restrict__ sums) {
  __shared__ uint4 wwS[1024];        // [k4*64+j]: {wl01,wl23,wr01,wr23} fp16 pairs, 16 KB
  __shared__ uint4 exS[8][8][17];    // [wave][node][c-group(16)+pad]
  __shared__ float scaleS[64], shiftS[64], biasS[64];
  __shared__ float redS[8][128];

  const int tid = threadIdx.x;

  for (int idx = tid; idx < 1024; idx += 512) {
    int k4 = idx >> 6, j = idx & 63;
    const float* pl = wl + j * 64 + k4 * 4;
    const float* pr = wr + j * 64 + k4 * 4;
    HU a0, a1, o0, o1;
    a0.h.x = (_Float16)pl[0]; a0.h.y = (_Float16)pl[1];
    a1.h.x = (_Float16)pl[2]; a1.h.y = (_Float16)pl[3];
    o0.h.x = (_Float16)pr[0]; o0.h.y = (_Float16)pr[1];
    o1.h.x = (_Float16)pr[2]; o1.h.y = (_Float16)pr[3];
    wwS[idx] = make_uint4(a0.u, a1.u, o0.u, o1.u);
  }
  if (tid < 64) {
    float sc = rsqrtf(v[tid] + 1e-5f) * g[tid];
    scaleS[tid] = sc;
    shiftS[tid] = be[tid] - m[tid] * sc;
    biasS[tid] = bl[tid];
  }
  __syncthreads();

  const int lane = tid & 63;
  const int wv = tid >> 6;
  const int slot = lane >> 4;   // 0..3 node slot
  const int c = lane & 15;      // channel quad (4 halfs = 8 B)
  const int wid = blockIdx.x * 8 + wv;
  const int nwaves = gridDim.x * 8;
  float accsum = 0.0f, accsum2 = 0.0f;

  for (int gidx = wid; gidx < (N_NODES / 8); gidx += nwaves) {
    const int nbase = gidx * 8;

    // ---- phase 1: gather 8 nodes (fp16) ----
#pragma unroll
    for (int sub = 0; sub < 2; ++sub) {
      const int node = nbase + sub * 4 + slot;
      const float2 ownraw = ((const float2*)(hin + (size_t)node * 64))[c];
      const int start = rowptr[node];
      const int deg = cnt[node];
      const int* cp = col + start;
      h2 a01 = (h2)(_Float16)0, a23 = (h2)(_Float16)0;
      int e = 0;
      for (; e + 4 <= deg; e += 4) {
        int s0 = cp[e], s1 = cp[e + 1], s2 = cp[e + 2], s3 = cp[e + 3];
        float2 r0 = ((const float2*)(hin + (size_t)s0 * 64))[c];
        float2 r1 = ((const float2*)(hin + (size_t)s1 * 64))[c];
        float2 r2 = ((const float2*)(hin + (size_t)s2 * 64))[c];
        float2 r3 = ((const float2*)(hin + (size_t)s3 * 64))[c];
        HU u;
        u.f = r0.x; a01 += u.h; u.f = r0.y; a23 += u.h;
        u.f = r1.x; a01 += u.h; u.f = r1.y; a23 += u.h;
        u.f = r2.x; a01 += u.h; u.f = r2.y; a23 += u.h;
        u.f = r3.x; a01 += u.h; u.f = r3.y; a23 += u.h;
      }
      for (; e < deg; ++e) {
        float2 r0 = ((const float2*)(hin + (size_t)cp[e] * 64))[c];
        HU u;
        u.f = r0.x; a01 += u.h; u.f = r0.y; a23 += u.h;
      }
      const _Float16 hinv = (_Float16)((deg > 0) ? (1.0f / (float)deg) : 0.0f);
      h2 vinv; vinv.x = hinv; vinv.y = hinv;
      a01 *= vinv; a23 *= vinv;
      HU wa0, wa1, wo0, wo1;
      wa0.h = a01; wa1.h = a23;
      wo0.f = ownraw.x; wo1.f = ownraw.y;
      exS[wv][sub * 4 + slot][c] = make_uint4(wa0.u, wa1.u, wo0.u, wo1.u);
    }
    // same-wave produce/consume; compiler inserts lgkmcnt waits -- no barrier

    // ---- phase 2: transform, lane = output channel j ----
    float out[8] = {0.f, 0.f, 0.f, 0.f, 0.f, 0.f, 0.f, 0.f};
#pragma unroll 4
    for (int k4 = 0; k4 < 16; ++k4) {
      uint4 w4 = wwS[k4 * 64 + lane];
      HU wl01, wl23, wr01, wr23;
      wl01.u = w4.x; wl23.u = w4.y; wr01.u = w4.z; wr23.u = w4.w;
#pragma unroll
      for (int n = 0; n < 8; ++n) {
        uint4 ao = exS[wv][n][k4];
        HU a01, a23, o01, o23;
        a01.u = ao.x; a23.u = ao.y; o01.u = ao.z; o23.u = ao.w;
        float t = out[n];
        t = fdot2f(a01.h, wl01.h, t);
        t = fdot2f(a23.h, wl23.h, t);
        t = fdot2f(o01.h, wr01.h, t);
        t = fdot2f(o23.h, wr23.h, t);
        out[n] = t;
      }
    }

    const float sc = scaleS[lane], sh = shiftS[lane], bi = biasS[lane];
#pragma unroll
    for (int n = 0; n < 8; ++n) {
      float o = fmaxf((out[n] + bi) * sc + sh, 0.0f);
      if (DO_SUMS) {
        accsum += o;
        accsum2 += coef[nbase + n] * o;
      }
      if (WRITE_OUT) hout[(size_t)(nbase + n) * 64 + lane] = (_Float16)o;
    }
  }

  if (DO_SUMS) {
    redS[wv][lane] = accsum;
    redS[wv][64 + lane] = accsum2;
    __syncthreads();
    if (wv == 0) {
      float t0 = 0.f, t1 = 0.f;
#pragma unroll
      for (int w = 0; w < 8; ++w) {
        t0 += redS[w][lane];
        t1 += redS[w][64 + lane];
      }
      atomicAdd(&sums[lane], t0);
      atomicAdd(&sums[64 + lane], t1);
    }
  }
}

// ---------------- collapsed layer 2 + classifier + sigmoid ----------------

__global__ void final_kernel(const float* __restrict__ sums,
                             const float* __restrict__ wl2, const float* __restrict__ bl2,
                             const float* __restrict__ wr2,
                             const float* __restrict__ cw1, const float* __restrict__ cb1,
                             const float* __restrict__ cw2, const float* __restrict__ cb2,
                             float* __restrict__ out) {
  __shared__ float maS[64], mhS[64], m3S[64], tS[64];
  int j = threadIdx.x;  // 64 threads
  float invN = 1.0f / (float)N_NODES;
  mhS[j] = sums[j] * invN;        // mean of h2
  maS[j] = sums[64 + j] * invN;   // mean of aggr3
  __syncthreads();
  float acc = bl2[j];
#pragma unroll
  for (int k = 0; k < 64; ++k)
    acc += wl2[j * 64 + k] * maS[k] + wr2[j * 64 + k] * mhS[k];
  m3S[j] = acc;
  __syncthreads();
  float c = cb1[j];
#pragma unroll
  for (int k = 0; k < 64; ++k) c += cw1[j * 64 + k] * m3S[k];
  tS[j] = fmaxf(c, 0.f);
  __syncthreads();
  float r = tS[j] * cw2[j];
#pragma unroll
  for (int off = 32; off > 0; off >>= 1) r += __shfl_down(r, off);
  if (j == 0) out[0] = 1.0f / (1.0f + expf(-(r + cb2[0])));
}

// ---------------- host launcher ----------------

extern "C" void kernel_launch(void* const* d_in, const int* in_sizes, int n_in,
                              void* d_out, int out_size, void* d_ws, size_t ws_size,
                              hipStream_t stream) {
  const float* x   = (const float*)d_in[0];
  const int* ei    = (const int*)d_in[1];
  const float* wl0 = (const float*)d_in[2];
  const float* bl0 = (const float*)d_in[3];
  const float* wr0 = (const float*)d_in[4];
  const float* wl1 = (const float*)d_in[5];
  const float* bl1 = (const float*)d_in[6];
  const float* wr1 = (const float*)d_in[7];
  const float* wl2 = (const float*)d_in[8];
  const float* bl2 = (const float*)d_in[9];
  const float* wr2 = (const float*)d_in[10];
  const float* g0  = (const float*)d_in[11];
  const float* be0 = (const float*)d_in[12];
  const float* m0  = (const float*)d_in[13];
  const float* v0  = (const float*)d_in[14];
  const float* g1  = (const float*)d_in[15];
  const float* be1 = (const float*)d_in[16];
  const float* m1  = (const float*)d_in[17];
  const float* v1  = (const float*)d_in[18];
  const float* cw1 = (const float*)d_in[19];
  const float* cb1 = (const float*)d_in[20];
  const float* cw2 = (const float*)d_in[21];
  const float* cb2 = (const float*)d_in[22];

  const int* srcp = ei;            // edge_index[0]
  const int* dstp = ei + N_EDGES;  // edge_index[1]

  char* ws = (char*)d_ws;
  size_t off = 0;
  auto alloc = [&](size_t bytes) {
    void* p = ws + off;
    off = align256(off + bytes);
    return p;
  };
  int* gfillD     = (int*)alloc((size_t)512 * 16 * 4);   // padded counters (64B apart)
  int* gfillS     = (int*)alloc((size_t)512 * 16 * 4);
  int* bbase      = (int*)alloc((size_t)512 * 4);
  int2* pairsD    = (int2*)alloc((size_t)NB * CAP * 8);  // ~16 MB
  int2* pairsS    = (int2*)alloc((size_t)NB * CAP * 8);  // ~16 MB
  int* rowptr     = (int*)alloc((size_t)N_NODES * 4);
  int* cnt        = (int*)alloc((size_t)N_NODES * 4);
  float* invdeg   = (float*)alloc((size_t)N_NODES * 4);
  float* coef     = (float*)alloc((size_t)N_NODES * 4);
  int* col        = (int*)alloc((size_t)N_EDGES * 4);
  float* sums     = (float*)alloc(128 * 4);
  _Float16* h0    = (_Float16*)alloc((size_t)N_NODES * 64 * 2);
  _Float16* h1    = (_Float16*)alloc((size_t)N_NODES * 64 * 2);
  (void)off; (void)ws_size; (void)in_sizes; (void)n_in; (void)out_size;

  hipMemsetAsync(gfillD, 0, (size_t)512 * 16 * 4, stream);
  hipMemsetAsync(gfillS, 0, (size_t)512 * 16 * 4, stream);
  hipMemsetAsync(sums, 0, 128 * 4, stream);

  partition_kernel<<<NBLK_PART, 256, 0, stream>>>(x, h0, srcp, dstp,
                                                  gfillD, gfillS, pairsD, pairsS);
  bscan_kernel<<<1, 512, 0, stream>>>(gfillD, bbase);
  csr_kernel<<<NB, 256, 0, stream>>>(pairsD, gfillD, bbase, col, rowptr, cnt, invdeg);
  coef_kernel<<<NB, 256, 0, stream>>>(pairsS, gfillS, invdeg, coef);

  layer_kernel<true, false><<<768, 512, 0, stream>>>(
      h0, rowptr, cnt, col, wl0, bl0, wr0, g0, be0, m0, v0, h1, nullptr, nullptr);
  layer_kernel<false, true><<<768, 512, 0, stream>>>(
      h1, rowptr, cnt, col, wl1, bl1, wr1, g1, be1, m1, v1, nullptr, coef, sums);
  final_kernel<<<1, 64, 0, stream>>>(sums, wl2, bl2, wr2, cw1, cb1, cw2, cb2,
                                     (float*)d_out);
}

// Round 9
// 200.294 us; speedup vs baseline: 1.6199x; 1.2341x over previous
//
#include <hip/hip_runtime.h>
#include <math.h>

#define N_NODES 100000
#define N_EDGES 1600000

static inline size_t align256(size_t x) { return (x + 255) & ~((size_t)255); }

constexpr int NB = (N_NODES + 255) / 256;  // 391 buckets (node>>8)
constexpr int CAP = 5120;                  // bucket capacity (avg 4092, max ~4400)
constexpr int PB = 512;                    // partition blocks
constexpr int PT = 512;                    // partition threads
constexpr int PCHUNK = N_EDGES / PB;       // 3125 (exact)

typedef _Float16 h2 __attribute__((ext_vector_type(2)));
typedef float f32x2 __attribute__((ext_vector_type(2)));
union HU { float f; unsigned u; h2 h; };

#if __has_builtin(__builtin_amdgcn_fdot2)
__device__ inline float fdot2f(h2 a, h2 b, float c) {
  return __builtin_amdgcn_fdot2(a, b, c, false);
}
#else
__device__ inline float fdot2f(h2 a, h2 b, float c) {
  return c + (float)a.x * (float)b.x + (float)a.y * (float)b.y;
}
#endif

#if __has_builtin(__builtin_amdgcn_cvt_pk_f32_fp8) && __has_builtin(__builtin_amdgcn_cvt_pk_fp8_f32)
#define FP8_HW 1
#else
#include <hip/hip_fp8.h>
#endif

// decode 4 fp8 (one u32) -> two f32x2
__device__ inline void dec4(unsigned u, f32x2& lo, f32x2& hi) {
#ifdef FP8_HW
  lo = __builtin_amdgcn_cvt_pk_f32_fp8((int)u, false);
  hi = __builtin_amdgcn_cvt_pk_f32_fp8((int)u, true);
#else
  __hip_fp8_e4m3 v0, v1, v2, v3;
  v0.__x = u & 0xFF; v1.__x = (u >> 8) & 0xFF;
  v2.__x = (u >> 16) & 0xFF; v3.__x = (u >> 24) & 0xFF;
  lo.x = (float)v0; lo.y = (float)v1; hi.x = (float)v2; hi.y = (float)v3;
#endif
}

__device__ inline unsigned enc4(float a, float b, float c, float d) {
#ifdef FP8_HW
  int w = __builtin_amdgcn_cvt_pk_fp8_f32(a, b, 0, false);
  w = __builtin_amdgcn_cvt_pk_fp8_f32(c, d, w, true);
  return (unsigned)w;
#else
  return (unsigned)__hip_fp8_e4m3(a).__x | ((unsigned)__hip_fp8_e4m3(b).__x << 8) |
         ((unsigned)__hip_fp8_e4m3(c).__x << 16) | ((unsigned)__hip_fp8_e4m3(d).__x << 24);
#endif
}

__device__ inline unsigned char enc1(float a) {
#ifdef FP8_HW
  return (unsigned char)(__builtin_amdgcn_cvt_pk_fp8_f32(a, a, 0, false) & 0xFF);
#else
  return (unsigned char)__hip_fp8_e4m3(a).__x;
#endif
}

// ---------------- K1: dual partition via block-local LDS counting sort ----------------
// Packed 4B entries; per-bucket runs written contiguously (dense lines).
// Global atomics: 2*391 per block only. Fused x -> fp8 convert at the end.

__global__ __launch_bounds__(PT) void partition_kernel(
    const float* __restrict__ x, unsigned char* __restrict__ h0,
    const int* __restrict__ src, const int* __restrict__ dst,
    int* __restrict__ gfillD, int* __restrict__ gfillS,
    unsigned* __restrict__ pairsD, unsigned* __restrict__ pairsS) {
  __shared__ unsigned ents[PCHUNK];
  __shared__ unsigned short bkt[PCHUNK];
  __shared__ int hist[NB], lfill[NB], delta[NB];
  __shared__ int sc[PT];

  const int blk = blockIdx.x, t = threadIdx.x;
  const int e0 = blk * PCHUNK;

#pragma unroll
  for (int pass = 0; pass < 2; ++pass) {
    const int* key = pass ? src : dst;    // bucket key
    const int* val = pass ? dst : src;    // payload
    int* gfill = pass ? gfillS : gfillD;
    unsigned* out = pass ? pairsS : pairsD;

    for (int i = t; i < NB; i += PT) hist[i] = 0;
    __syncthreads();
    for (int i = t; i < PCHUNK; i += PT) atomicAdd(&hist[key[e0 + i] >> 8], 1);
    __syncthreads();
    int v = (t < NB) ? hist[t] : 0;
    sc[t] = v;
    __syncthreads();
    for (int off = 1; off < PT; off <<= 1) {
      int a = (t >= off) ? sc[t - off] : 0;
      __syncthreads();
      sc[t] += a;
      __syncthreads();
    }
    if (t < NB) {
      int excl = sc[t] - v;
      lfill[t] = excl;
      int gb = atomicAdd(&gfill[t * 16], v);
      delta[t] = t * CAP + gb - excl;
    }
    __syncthreads();
    for (int i = t; i < PCHUNK; i += PT) {
      int k = key[e0 + i], w = val[e0 + i];
      int b = k >> 8;
      int p = atomicAdd(&lfill[b], 1);
      ents[p] = (unsigned)w | ((unsigned)(k & 255) << 17);
      bkt[p] = (unsigned short)b;
    }
    __syncthreads();
    for (int i = t; i < PCHUNK; i += PT) out[delta[bkt[i]] + i] = ents[i];
    __syncthreads();
  }

  // fused x -> fp8 convert (grid-stride)
  const int gtid = blk * PT + t;
  const int nth = gridDim.x * PT;
  for (int i = gtid; i < N_NODES * 8; i += nth) {
    float4 a = ((const float4*)x)[2 * i];
    float4 b = ((const float4*)x)[2 * i + 1];
    ((uint2*)h0)[i] = make_uint2(enc4(a.x, a.y, a.z, a.w), enc4(b.x, b.y, b.z, b.w));
  }
}

// ---------------- K2: exclusive scan of 391 dst-bucket counts (single block) ----------------

__global__ __launch_bounds__(512) void bscan_kernel(const int* __restrict__ bfill,
                                                    int* __restrict__ bbase) {
  __shared__ int s[512];
  int t = threadIdx.x;
  int v = (t < NB) ? bfill[t * 16] : 0;
  s[t] = v;
  __syncthreads();
  for (int off = 1; off < 512; off <<= 1) {
    int a = (t >= off) ? s[t - off] : 0;
    __syncthreads();
    s[t] += a;
    __syncthreads();
  }
  if (t < NB) bbase[t] = s[t] - v;  // exclusive
}

// ---------------- K3: per-dst-bucket LDS counting sort -> col, rowptr, cnt, invdeg ----------------
// entry = src | (dst&255)<<17

__global__ __launch_bounds__(256) void csr_kernel(const unsigned* __restrict__ pairs,
                                                  const int* __restrict__ bfill,
                                                  const int* __restrict__ bbase,
                                                  int* __restrict__ col,
                                                  int* __restrict__ rowptr,
                                                  int* __restrict__ cnt,
                                                  float* __restrict__ invdeg) {
  __shared__ int hist[256], sc[256], offs[256];
  const int b = blockIdx.x;
  const int t = threadIdx.x;
  hist[t] = 0;
  __syncthreads();
  const int count = bfill[b * 16];
  const int base = bbase[b];
  const unsigned* bp = pairs + (size_t)b * CAP;
  for (int i = t; i < count; i += 256) atomicAdd(&hist[(bp[i] >> 17) & 255], 1);
  __syncthreads();
  int v = hist[t];
  sc[t] = v;
  __syncthreads();
  for (int off = 1; off < 256; off <<= 1) {
    int a = (t >= off) ? sc[t - off] : 0;
    __syncthreads();
    sc[t] += a;
    __syncthreads();
  }
  const int excl = sc[t] - v;
  offs[t] = base + excl;
  const int node = b * 256 + t;
  if (node < N_NODES) {
    rowptr[node] = base + excl;
    cnt[node] = v;
    invdeg[node] = 1.0f / (float)((v > 0) ? v : 1);
  }
  __syncthreads();
  for (int i = t; i < count; i += 256) {
    unsigned e = bp[i];
    int p = atomicAdd(&offs[(e >> 17) & 255], 1);
    col[p] = (int)(e & 0x1FFFF);
  }
}

// ---------------- K4: coef via per-src-bucket LDS accumulation ----------------
// entry = dst | (src&255)<<17 ; coef[s] = sum invdeg[dst] over out-edges.

__global__ __launch_bounds__(256) void coef_kernel(const unsigned* __restrict__ pairsS,
                                                   const int* __restrict__ gfillS,
                                                   const float* __restrict__ invdeg,
                                                   float* __restrict__ coef) {
  __shared__ float cl[256];
  const int b = blockIdx.x;
  const int t = threadIdx.x;
  cl[t] = 0.0f;
  __syncthreads();
  const int count = gfillS[b * 16];
  const unsigned* bp = pairsS + (size_t)b * CAP;
  for (int i = t; i < count; i += 256) {
    unsigned e = bp[i];
    atomicAdd(&cl[(e >> 17) & 255], invdeg[e & 0x1FFFF]);
  }
  __syncthreads();
  const int node = b * 256 + t;
  if (node < N_NODES) coef[node] = cl[t];
}

// ---------------- fused SAGEConv + BN + ReLU (layers 0 and 1), fp8 h ----------------
// block = 512 = 8 waves; each wave does 8 nodes per round.
// h rows are 64B (one cache line): 16 lanes x u32 (4 fp8 each). f32 accumulate,
// fp16 exchange + weights, f32 out. DO_SUMS as before (collapsed layer 2).

template <bool WRITE_OUT, bool DO_SUMS>
__global__ __launch_bounds__(512) void layer_kernel(
    const unsigned char* __restrict__ hin, const int* __restrict__ rowptr,
    const int* __restrict__ cnt, const int* __restrict__ col,
    const float* __restrict__ wl, const float* __restrict__ bl,
    const float* __restrict__ wr,
    const float* __restrict__ g, const float* __restrict__ be,
    const float* __restrict__ m, const float* __restrict__ v,
    unsigned char* __restrict__ hout, const float* __restrict__ coef,
    float* __restrict__ sums) {
  __shared__ uint4 wwS[1024];        // [k4*64+j]: {wl01,wl23,wr01,wr23} fp16 pairs, 16 KB
  __shared__ uint4 exS[8][8][17];    // [wave][node][c-group(16)+pad]
  __shared__ float scaleS[64], shiftS[64], biasS[64];
  __shared__ float redS[8][128];

  const int tid = threadIdx.x;

  for (int idx = tid; idx < 1024; idx += 512) {
    int k4 = idx >> 6, j = idx & 63;
    const float* pl = wl + j * 64 + k4 * 4;
    const float* pr = wr + j * 64 + k4 * 4;
    HU a0, a1, o0, o1;
    a0.h.x = (_Float16)pl[0]; a0.h.y = (_Float16)pl[1];
    a1.h.x = (_Float16)pl[2]; a1.h.y = (_Float16)pl[3];
    o0.h.x = (_Float16)pr[0]; o0.h.y = (_Float16)pr[1];
    o1.h.x = (_Float16)pr[2]; o1.h.y = (_Float16)pr[3];
    wwS[idx] = make_uint4(a0.u, a1.u, o0.u, o1.u);
  }
  if (tid < 64) {
    float sc = rsqrtf(v[tid] + 1e-5f) * g[tid];
    scaleS[tid] = sc;
    shiftS[tid] = be[tid] - m[tid] * sc;
    biasS[tid] = bl[tid];
  }
  __syncthreads();

  const int lane = tid & 63;
  const int wv = tid >> 6;
  const int slot = lane >> 4;   // 0..3 node slot
  const int c = lane & 15;      // channel quad (4 fp8 = 4 B)
  const int wid = blockIdx.x * 8 + wv;
  const int nwaves = gridDim.x * 8;
  const unsigned* __restrict__ hrows = (const unsigned*)hin;  // 16 u32 per row
  float accsum = 0.0f, accsum2 = 0.0f;

  for (int gidx = wid; gidx < (N_NODES / 8); gidx += nwaves) {
    const int nbase = gidx * 8;

    // ---- phase 1: gather 8 nodes (fp8 rows, f32 accumulate) ----
#pragma unroll
    for (int sub = 0; sub < 2; ++sub) {
      const int node = nbase + sub * 4 + slot;
      const unsigned uo = hrows[node * 16 + c];
      const int start = rowptr[node];
      const int deg = cnt[node];
      const int* cp = col + start;
      f32x2 a01 = {0.f, 0.f}, a23 = {0.f, 0.f};
      int e = 0;
      for (; e + 4 <= deg; e += 4) {
        unsigned u0 = hrows[cp[e] * 16 + c];
        unsigned u1 = hrows[cp[e + 1] * 16 + c];
        unsigned u2 = hrows[cp[e + 2] * 16 + c];
        unsigned u3 = hrows[cp[e + 3] * 16 + c];
        f32x2 lo, hi;
        dec4(u0, lo, hi); a01 += lo; a23 += hi;
        dec4(u1, lo, hi); a01 += lo; a23 += hi;
        dec4(u2, lo, hi); a01 += lo; a23 += hi;
        dec4(u3, lo, hi); a01 += lo; a23 += hi;
      }
      for (; e < deg; ++e) {
        f32x2 lo, hi;
        dec4(hrows[cp[e] * 16 + c], lo, hi);
        a01 += lo; a23 += hi;
      }
      const float inv = (deg > 0) ? (1.0f / (float)deg) : 0.0f;
      a01 *= inv; a23 *= inv;
      f32x2 olo, ohi;
      dec4(uo, olo, ohi);
      HU wa0, wa1, wo0, wo1;
      wa0.h.x = (_Float16)a01.x; wa0.h.y = (_Float16)a01.y;
      wa1.h.x = (_Float16)a23.x; wa1.h.y = (_Float16)a23.y;
      wo0.h.x = (_Float16)olo.x; wo0.h.y = (_Float16)olo.y;
      wo1.h.x = (_Float16)ohi.x; wo1.h.y = (_Float16)ohi.y;
      exS[wv][sub * 4 + slot][c] = make_uint4(wa0.u, wa1.u, wo0.u, wo1.u);
    }
    // same-wave produce/consume; compiler inserts lgkmcnt waits -- no barrier

    // ---- phase 2: transform, lane = output channel j ----
    float out[8] = {0.f, 0.f, 0.f, 0.f, 0.f, 0.f, 0.f, 0.f};
#pragma unroll 4
    for (int k4 = 0; k4 < 16; ++k4) {
      uint4 w4 = wwS[k4 * 64 + lane];
      HU wl01, wl23, wr01, wr23;
      wl01.u = w4.x; wl23.u = w4.y; wr01.u = w4.z; wr23.u = w4.w;
#pragma unroll
      for (int n = 0; n < 8; ++n) {
        uint4 ao = exS[wv][n][k4];
        HU a01, a23, o01, o23;
        a01.u = ao.x; a23.u = ao.y; o01.u = ao.z; o23.u = ao.w;
        float t = out[n];
        t = fdot2f(a01.h, wl01.h, t);
        t = fdot2f(a23.h, wl23.h, t);
        t = fdot2f(o01.h, wr01.h, t);
        t = fdot2f(o23.h, wr23.h, t);
        out[n] = t;
      }
    }

    const float sc = scaleS[lane], sh = shiftS[lane], bi = biasS[lane];
#pragma unroll
    for (int n = 0; n < 8; ++n) {
      float o = fmaxf((out[n] + bi) * sc + sh, 0.0f);
      if (DO_SUMS) {
        accsum += o;
        accsum2 += coef[nbase + n] * o;
      }
      if (WRITE_OUT) hout[(size_t)(nbase + n) * 64 + lane] = enc1(o);
    }
  }

  if (DO_SUMS) {
    redS[wv][lane] = accsum;
    redS[wv][64 + lane] = accsum2;
    __syncthreads();
    if (wv == 0) {
      float t0 = 0.f, t1 = 0.f;
#pragma unroll
      for (int w = 0; w < 8; ++w) {
        t0 += redS[w][lane];
        t1 += redS[w][64 + lane];
      }
      atomicAdd(&sums[lane], t0);
      atomicAdd(&sums[64 + lane], t1);
    }
  }
}

// ---------------- collapsed layer 2 + classifier + sigmoid ----------------

__global__ void final_kernel(const float* __restrict__ sums,
                             const float* __restrict__ wl2, const float* __restrict__ bl2,
                             const float* __restrict__ wr2,
                             const float* __restrict__ cw1, const float* __restrict__ cb1,
                             const float* __restrict__ cw2, const float* __restrict__ cb2,
                             float* __restrict__ out) {
  __shared__ float maS[64], mhS[64], m3S[64], tS[64];
  int j = threadIdx.x;  // 64 threads
  float invN = 1.0f / (float)N_NODES;
  mhS[j] = sums[j] * invN;        // mean of h2
  maS[j] = sums[64 + j] * invN;   // mean of aggr3
  __syncthreads();
  float acc = bl2[j];
#pragma unroll
  for (int k = 0; k < 64; ++k)
    acc += wl2[j * 64 + k] * maS[k] + wr2[j * 64 + k] * mhS[k];
  m3S[j] = acc;
  __syncthreads();
  float c = cb1[j];
#pragma unroll
  for (int k = 0; k < 64; ++k) c += cw1[j * 64 + k] * m3S[k];
  tS[j] = fmaxf(c, 0.f);
  __syncthreads();
  float r = tS[j] * cw2[j];
#pragma unroll
  for (int off = 32; off > 0; off >>= 1) r += __shfl_down(r, off);
  if (j == 0) out[0] = 1.0f / (1.0f + expf(-(r + cb2[0])));
}

// ---------------- host launcher ----------------

extern "C" void kernel_launch(void* const* d_in, const int* in_sizes, int n_in,
                              void* d_out, int out_size, void* d_ws, size_t ws_size,
                              hipStream_t stream) {
  const float* x   = (const float*)d_in[0];
  const int* ei    = (const int*)d_in[1];
  const float* wl0 = (const float*)d_in[2];
  const float* bl0 = (const float*)d_in[3];
  const float* wr0 = (const float*)d_in[4];
  const float* wl1 = (const float*)d_in[5];
  const float* bl1 = (const float*)d_in[6];
  const float* wr1 = (const float*)d_in[7];
  const float* wl2 = (const float*)d_in[8];
  const float* bl2 = (const float*)d_in[9];
  const float* wr2 = (const float*)d_in[10];
  const float* g0  = (const float*)d_in[11];
  const float* be0 = (const float*)d_in[12];
  const float* m0  = (const float*)d_in[13];
  const float* v0  = (const float*)d_in[14];
  const float* g1  = (const float*)d_in[15];
  const float* be1 = (const float*)d_in[16];
  const float* m1  = (const float*)d_in[17];
  const float* v1  = (const float*)d_in[18];
  const float* cw1 = (const float*)d_in[19];
  const float* cb1 = (const float*)d_in[20];
  const float* cw2 = (const float*)d_in[21];
  const float* cb2 = (const float*)d_in[22];

  const int* srcp = ei;            // edge_index[0]
  const int* dstp = ei + N_EDGES;  // edge_index[1]

  char* ws = (char*)d_ws;
  size_t off = 0;
  auto alloc = [&](size_t bytes) {
    void* p = ws + off;
    off = align256(off + bytes);
    return p;
  };
  int* gfillD      = (int*)alloc((size_t)512 * 16 * 4);   // padded counters (64B apart)
  int* gfillS      = (int*)alloc((size_t)512 * 16 * 4);
  int* bbase       = (int*)alloc((size_t)512 * 4);
  unsigned* pairsD = (unsigned*)alloc((size_t)NB * CAP * 4);  // ~8 MB
  unsigned* pairsS = (unsigned*)alloc((size_t)NB * CAP * 4);  // ~8 MB
  int* rowptr      = (int*)alloc((size_t)N_NODES * 4);
  int* cnt         = (int*)alloc((size_t)N_NODES * 4);
  float* invdeg    = (float*)alloc((size_t)N_NODES * 4);
  float* coef      = (float*)alloc((size_t)N_NODES * 4);
  int* col         = (int*)alloc((size_t)N_EDGES * 4);
  float* sums      = (float*)alloc(128 * 4);
  unsigned char* h0 = (unsigned char*)alloc((size_t)N_NODES * 64);
  unsigned char* h1 = (unsigned char*)alloc((size_t)N_NODES * 64);
  (void)off; (void)ws_size; (void)in_sizes; (void)n_in; (void)out_size;

  hipMemsetAsync(gfillD, 0, (size_t)512 * 16 * 4, stream);
  hipMemsetAsync(gfillS, 0, (size_t)512 * 16 * 4, stream);
  hipMemsetAsync(sums, 0, 128 * 4, stream);

  partition_kernel<<<PB, PT, 0, stream>>>(x, h0, srcp, dstp,
                                          gfillD, gfillS, pairsD, pairsS);
  bscan_kernel<<<1, 512, 0, stream>>>(gfillD, bbase);
  csr_kernel<<<NB, 256, 0, stream>>>(pairsD, gfillD, bbase, col, rowptr, cnt, invdeg);
  coef_kernel<<<NB, 256, 0, stream>>>(pairsS, gfillS, invdeg, coef);

  layer_kernel<true, false><<<768, 512, 0, stream>>>(
      h0, rowptr, cnt, col, wl0, bl0, wr0, g0, be0, m0, v0, h1, nullptr, nullptr);
  layer_kernel<false, true><<<768, 512, 0, stream>>>(
      h1, rowptr, cnt, col, wl1, bl1, wr1, g1, be1, m1, v1, nullptr, coef, sums);
  final_kernel<<<1, 64, 0, stream>>>(sums, wl2, bl2, wr2, cw1, cb1, cw2, cb2,
                                     (float*)d_out);
}

// Round 10
// 188.881 us; speedup vs baseline: 1.7177x; 1.0604x over previous
//
#include <hip/hip_runtime.h>
#include <math.h>

#define N_NODES 100000
#define N_EDGES 1600000

static inline size_t align256(size_t x) { return (x + 255) & ~((size_t)255); }

constexpr int NB = (N_NODES + 255) / 256;  // 391 buckets (node>>8)
constexpr int CAP = 5120;                  // bucket capacity (avg 4092, max ~4400)
constexpr int PB = 512;                    // partition blocks
constexpr int PT = 512;                    // partition threads
constexpr int PCHUNK = N_EDGES / PB;       // 3125 (exact)

typedef _Float16 h2 __attribute__((ext_vector_type(2)));
typedef float f32x2 __attribute__((ext_vector_type(2)));
union HU { float f; unsigned u; h2 h; };

#if __has_builtin(__builtin_amdgcn_fdot2)
__device__ inline float fdot2f(h2 a, h2 b, float c) {
  return __builtin_amdgcn_fdot2(a, b, c, false);
}
#else
__device__ inline float fdot2f(h2 a, h2 b, float c) {
  return c + (float)a.x * (float)b.x + (float)a.y * (float)b.y;
}
#endif

#if __has_builtin(__builtin_amdgcn_cvt_pk_f32_fp8) && __has_builtin(__builtin_amdgcn_cvt_pk_fp8_f32)
#define FP8_HW 1
#else
#include <hip/hip_fp8.h>
#endif

// decode 4 fp8 (one u32) -> two f32x2
__device__ inline void dec4(unsigned u, f32x2& lo, f32x2& hi) {
#ifdef FP8_HW
  lo = __builtin_amdgcn_cvt_pk_f32_fp8((int)u, false);
  hi = __builtin_amdgcn_cvt_pk_f32_fp8((int)u, true);
#else
  __hip_fp8_e4m3 v0, v1, v2, v3;
  v0.__x = u & 0xFF; v1.__x = (u >> 8) & 0xFF;
  v2.__x = (u >> 16) & 0xFF; v3.__x = (u >> 24) & 0xFF;
  lo.x = (float)v0; lo.y = (float)v1; hi.x = (float)v2; hi.y = (float)v3;
#endif
}

__device__ inline unsigned enc4(float a, float b, float c, float d) {
#ifdef FP8_HW
  int w = __builtin_amdgcn_cvt_pk_fp8_f32(a, b, 0, false);
  w = __builtin_amdgcn_cvt_pk_fp8_f32(c, d, w, true);
  return (unsigned)w;
#else
  return (unsigned)__hip_fp8_e4m3(a).__x | ((unsigned)__hip_fp8_e4m3(b).__x << 8) |
         ((unsigned)__hip_fp8_e4m3(c).__x << 16) | ((unsigned)__hip_fp8_e4m3(d).__x << 24);
#endif
}

__device__ inline unsigned char enc1(float a) {
#ifdef FP8_HW
  return (unsigned char)(__builtin_amdgcn_cvt_pk_fp8_f32(a, a, 0, false) & 0xFF);
#else
  return (unsigned char)__hip_fp8_e4m3(a).__x;
#endif
}

// ---------------- K1: dual partition via block-local LDS counting sort ----------------

__global__ __launch_bounds__(PT) void partition_kernel(
    const float* __restrict__ x, unsigned char* __restrict__ h0,
    const int* __restrict__ src, const int* __restrict__ dst,
    int* __restrict__ gfillD, int* __restrict__ gfillS,
    unsigned* __restrict__ pairsD, unsigned* __restrict__ pairsS) {
  __shared__ unsigned ents[PCHUNK];
  __shared__ unsigned short bkt[PCHUNK];
  __shared__ int hist[NB], lfill[NB], delta[NB];
  __shared__ int sc[PT];

  const int blk = blockIdx.x, t = threadIdx.x;
  const int e0 = blk * PCHUNK;

#pragma unroll
  for (int pass = 0; pass < 2; ++pass) {
    const int* key = pass ? src : dst;    // bucket key
    const int* val = pass ? dst : src;    // payload
    int* gfill = pass ? gfillS : gfillD;
    unsigned* out = pass ? pairsS : pairsD;

    for (int i = t; i < NB; i += PT) hist[i] = 0;
    __syncthreads();
    for (int i = t; i < PCHUNK; i += PT) atomicAdd(&hist[key[e0 + i] >> 8], 1);
    __syncthreads();
    int v = (t < NB) ? hist[t] : 0;
    sc[t] = v;
    __syncthreads();
    for (int off = 1; off < PT; off <<= 1) {
      int a = (t >= off) ? sc[t - off] : 0;
      __syncthreads();
      sc[t] += a;
      __syncthreads();
    }
    if (t < NB) {
      int excl = sc[t] - v;
      lfill[t] = excl;
      int gb = atomicAdd(&gfill[t * 16], v);
      delta[t] = t * CAP + gb - excl;
    }
    __syncthreads();
    for (int i = t; i < PCHUNK; i += PT) {
      int k = key[e0 + i], w = val[e0 + i];
      int b = k >> 8;
      int p = atomicAdd(&lfill[b], 1);
      ents[p] = (unsigned)w | ((unsigned)(k & 255) << 17);
      bkt[p] = (unsigned short)b;
    }
    __syncthreads();
    for (int i = t; i < PCHUNK; i += PT) out[delta[bkt[i]] + i] = ents[i];
    __syncthreads();
  }

  // fused x -> fp8 convert (grid-stride)
  const int gtid = blk * PT + t;
  const int nth = gridDim.x * PT;
  for (int i = gtid; i < N_NODES * 8; i += nth) {
    float4 a = ((const float4*)x)[2 * i];
    float4 b = ((const float4*)x)[2 * i + 1];
    ((uint2*)h0)[i] = make_uint2(enc4(a.x, a.y, a.z, a.w), enc4(b.x, b.y, b.z, b.w));
  }
}

// ---------------- K2: exclusive scan of 391 dst-bucket counts (single block) ----------------

__global__ __launch_bounds__(512) void bscan_kernel(const int* __restrict__ bfill,
                                                    int* __restrict__ bbase) {
  __shared__ int s[512];
  int t = threadIdx.x;
  int v = (t < NB) ? bfill[t * 16] : 0;
  s[t] = v;
  __syncthreads();
  for (int off = 1; off < 512; off <<= 1) {
    int a = (t >= off) ? s[t - off] : 0;
    __syncthreads();
    s[t] += a;
    __syncthreads();
  }
  if (t < NB) bbase[t] = s[t] - v;  // exclusive
}

// ---------------- K3: per-dst-bucket LDS counting sort -> col, rowptr, cnt, invdeg ----------------
// entry = src | (dst&255)<<17

__global__ __launch_bounds__(256) void csr_kernel(const unsigned* __restrict__ pairs,
                                                  const int* __restrict__ bfill,
                                                  const int* __restrict__ bbase,
                                                  int* __restrict__ col,
                                                  int* __restrict__ rowptr,
                                                  int* __restrict__ cnt,
                                                  float* __restrict__ invdeg) {
  __shared__ int hist[256], sc[256], offs[256];
  const int b = blockIdx.x;
  const int t = threadIdx.x;
  hist[t] = 0;
  __syncthreads();
  const int count = bfill[b * 16];
  const int base = bbase[b];
  const unsigned* bp = pairs + (size_t)b * CAP;
  for (int i = t; i < count; i += 256) atomicAdd(&hist[(bp[i] >> 17) & 255], 1);
  __syncthreads();
  int v = hist[t];
  sc[t] = v;
  __syncthreads();
  for (int off = 1; off < 256; off <<= 1) {
    int a = (t >= off) ? sc[t - off] : 0;
    __syncthreads();
    sc[t] += a;
    __syncthreads();
  }
  const int excl = sc[t] - v;
  offs[t] = base + excl;
  const int node = b * 256 + t;
  if (node < N_NODES) {
    rowptr[node] = base + excl;
    cnt[node] = v;
    invdeg[node] = 1.0f / (float)((v > 0) ? v : 1);
  }
  __syncthreads();
  for (int i = t; i < count; i += 256) {
    unsigned e = bp[i];
    int p = atomicAdd(&offs[(e >> 17) & 255], 1);
    col[p] = (int)(e & 0x1FFFF);
  }
}

// ---------------- K4: coef via per-src-bucket LDS accumulation ----------------
// entry = dst | (src&255)<<17 ; coef[s] = sum invdeg[dst] over out-edges.

__global__ __launch_bounds__(256) void coef_kernel(const unsigned* __restrict__ pairsS,
                                                   const int* __restrict__ gfillS,
                                                   const float* __restrict__ invdeg,
                                                   float* __restrict__ coef) {
  __shared__ float cl[256];
  const int b = blockIdx.x;
  const int t = threadIdx.x;
  cl[t] = 0.0f;
  __syncthreads();
  const int count = gfillS[b * 16];
  const unsigned* bp = pairsS + (size_t)b * CAP;
  for (int i = t; i < count; i += 256) {
    unsigned e = bp[i];
    atomicAdd(&cl[(e >> 17) & 255], invdeg[e & 0x1FFFF]);
  }
  __syncthreads();
  const int node = b * 256 + t;
  if (node < N_NODES) coef[node] = cl[t];
}

// ---------------- fused SAGEConv + BN + ReLU (layers 0 and 1), fp8 h ----------------
// block = 512 = 8 waves; each wave does 8 nodes per round.
// Phase 1 (NEW): 8 node-slots per wave (slot=lane>>3, c=lane&7, uint2 = 8 fp8
//   channels per lane). All 8 nodes gather concurrently -> 32 outstanding
//   row-requests per wave (2x R9), no sequential sub-passes.
// Phase 2: unchanged (lane = output channel, fp16 dot2 vs LDS weights).

template <bool WRITE_OUT, bool DO_SUMS>
__global__ __launch_bounds__(512) void layer_kernel(
    const unsigned char* __restrict__ hin, const int* __restrict__ rowptr,
    const int* __restrict__ cnt, const int* __restrict__ col,
    const float* __restrict__ wl, const float* __restrict__ bl,
    const float* __restrict__ wr,
    const float* __restrict__ g, const float* __restrict__ be,
    const float* __restrict__ m, const float* __restrict__ v,
    unsigned char* __restrict__ hout, const float* __restrict__ coef,
    float* __restrict__ sums) {
  __shared__ uint4 wwS[1024];        // [k4*64+j]: {wl01,wl23,wr01,wr23} fp16 pairs, 16 KB
  __shared__ uint4 exS[8][8][17];    // [wave][node][k4(16)+pad]: {a01,a23,o01,o23}
  __shared__ float scaleS[64], shiftS[64], biasS[64];
  __shared__ float redS[8][128];

  const int tid = threadIdx.x;

  for (int idx = tid; idx < 1024; idx += 512) {
    int k4 = idx >> 6, j = idx & 63;
    const float* pl = wl + j * 64 + k4 * 4;
    const float* pr = wr + j * 64 + k4 * 4;
    HU a0, a1, o0, o1;
    a0.h.x = (_Float16)pl[0]; a0.h.y = (_Float16)pl[1];
    a1.h.x = (_Float16)pl[2]; a1.h.y = (_Float16)pl[3];
    o0.h.x = (_Float16)pr[0]; o0.h.y = (_Float16)pr[1];
    o1.h.x = (_Float16)pr[2]; o1.h.y = (_Float16)pr[3];
    wwS[idx] = make_uint4(a0.u, a1.u, o0.u, o1.u);
  }
  if (tid < 64) {
    float sc = rsqrtf(v[tid] + 1e-5f) * g[tid];
    scaleS[tid] = sc;
    shiftS[tid] = be[tid] - m[tid] * sc;
    biasS[tid] = bl[tid];
  }
  __syncthreads();

  const int lane = tid & 63;
  const int wv = tid >> 6;
  const int slot = lane >> 3;   // 0..7 node slot
  const int c = lane & 7;       // channel octet (8 fp8 = 8 B)
  const int wid = blockIdx.x * 8 + wv;
  const int nwaves = gridDim.x * 8;
  const uint2* __restrict__ hrows = (const uint2*)hin;  // 8 uint2 per 64B row
  float accsum = 0.0f, accsum2 = 0.0f;

  for (int gidx = wid; gidx < (N_NODES / 8); gidx += nwaves) {
    const int nbase = gidx * 8;

    // ---- phase 1: gather 8 nodes concurrently (fp8, f32 accumulate) ----
    {
      const int node = nbase + slot;
      const uint2 uo = hrows[node * 8 + c];
      const int start = rowptr[node];
      const int deg = cnt[node];
      const int* cp = col + start;
      f32x2 a01 = {0.f, 0.f}, a23 = {0.f, 0.f}, a45 = {0.f, 0.f}, a67 = {0.f, 0.f};
      int e = 0;
      for (; e + 4 <= deg; e += 4) {
        uint2 u0 = hrows[cp[e] * 8 + c];
        uint2 u1 = hrows[cp[e + 1] * 8 + c];
        uint2 u2 = hrows[cp[e + 2] * 8 + c];
        uint2 u3 = hrows[cp[e + 3] * 8 + c];
        f32x2 lo, hi;
        dec4(u0.x, lo, hi); a01 += lo; a23 += hi;
        dec4(u0.y, lo, hi); a45 += lo; a67 += hi;
        dec4(u1.x, lo, hi); a01 += lo; a23 += hi;
        dec4(u1.y, lo, hi); a45 += lo; a67 += hi;
        dec4(u2.x, lo, hi); a01 += lo; a23 += hi;
        dec4(u2.y, lo, hi); a45 += lo; a67 += hi;
        dec4(u3.x, lo, hi); a01 += lo; a23 += hi;
        dec4(u3.y, lo, hi); a45 += lo; a67 += hi;
      }
      for (; e < deg; ++e) {
        uint2 u0 = hrows[cp[e] * 8 + c];
        f32x2 lo, hi;
        dec4(u0.x, lo, hi); a01 += lo; a23 += hi;
        dec4(u0.y, lo, hi); a45 += lo; a67 += hi;
      }
      const float inv = (deg > 0) ? (1.0f / (float)deg) : 0.0f;
      a01 *= inv; a23 *= inv; a45 *= inv; a67 *= inv;
      f32x2 olo, ohi;
      HU wa0, wa1, wo0, wo1;
      // channels 8c..8c+3 -> k4 = 2c
      dec4(uo.x, olo, ohi);
      wa0.h.x = (_Float16)a01.x; wa0.h.y = (_Float16)a01.y;
      wa1.h.x = (_Float16)a23.x; wa1.h.y = (_Float16)a23.y;
      wo0.h.x = (_Float16)olo.x; wo0.h.y = (_Float16)olo.y;
      wo1.h.x = (_Float16)ohi.x; wo1.h.y = (_Float16)ohi.y;
      exS[wv][slot][2 * c] = make_uint4(wa0.u, wa1.u, wo0.u, wo1.u);
      // channels 8c+4..8c+7 -> k4 = 2c+1
      dec4(uo.y, olo, ohi);
      wa0.h.x = (_Float16)a45.x; wa0.h.y = (_Float16)a45.y;
      wa1.h.x = (_Float16)a67.x; wa1.h.y = (_Float16)a67.y;
      wo0.h.x = (_Float16)olo.x; wo0.h.y = (_Float16)olo.y;
      wo1.h.x = (_Float16)ohi.x; wo1.h.y = (_Float16)ohi.y;
      exS[wv][slot][2 * c + 1] = make_uint4(wa0.u, wa1.u, wo0.u, wo1.u);
    }
    // same-wave produce/consume; compiler inserts lgkmcnt waits -- no barrier

    // ---- phase 2: transform, lane = output channel j ----
    float out[8] = {0.f, 0.f, 0.f, 0.f, 0.f, 0.f, 0.f, 0.f};
#pragma unroll 4
    for (int k4 = 0; k4 < 16; ++k4) {
      uint4 w4 = wwS[k4 * 64 + lane];
      HU wl01, wl23, wr01, wr23;
      wl01.u = w4.x; wl23.u = w4.y; wr01.u = w4.z; wr23.u = w4.w;
#pragma unroll
      for (int n = 0; n < 8; ++n) {
        uint4 ao = exS[wv][n][k4];
        HU a01, a23, o01, o23;
        a01.u = ao.x; a23.u = ao.y; o01.u = ao.z; o23.u = ao.w;
        float t = out[n];
        t = fdot2f(a01.h, wl01.h, t);
        t = fdot2f(a23.h, wl23.h, t);
        t = fdot2f(o01.h, wr01.h, t);
        t = fdot2f(o23.h, wr23.h, t);
        out[n] = t;
      }
    }

    const float sc = scaleS[lane], sh = shiftS[lane], bi = biasS[lane];
#pragma unroll
    for (int n = 0; n < 8; ++n) {
      float o = fmaxf((out[n] + bi) * sc + sh, 0.0f);
      if (DO_SUMS) {
        accsum += o;
        accsum2 += coef[nbase + n] * o;
      }
      if (WRITE_OUT) hout[(size_t)(nbase + n) * 64 + lane] = enc1(o);
    }
  }

  if (DO_SUMS) {
    redS[wv][lane] = accsum;
    redS[wv][64 + lane] = accsum2;
    __syncthreads();
    if (wv == 0) {
      float t0 = 0.f, t1 = 0.f;
#pragma unroll
      for (int w = 0; w < 8; ++w) {
        t0 += redS[w][lane];
        t1 += redS[w][64 + lane];
      }
      atomicAdd(&sums[lane], t0);
      atomicAdd(&sums[64 + lane], t1);
    }
  }
}

// ---------------- collapsed layer 2 + classifier + sigmoid ----------------

__global__ void final_kernel(const float* __restrict__ sums,
                             const float* __restrict__ wl2, const float* __restrict__ bl2,
                             const float* __restrict__ wr2,
                             const float* __restrict__ cw1, const float* __restrict__ cb1,
                             const float* __restrict__ cw2, const float* __restrict__ cb2,
                             float* __restrict__ out) {
  __shared__ float maS[64], mhS[64], m3S[64], tS[64];
  int j = threadIdx.x;  // 64 threads
  float invN = 1.0f / (float)N_NODES;
  mhS[j] = sums[j] * invN;        // mean of h2
  maS[j] = sums[64 + j] * invN;   // mean of aggr3
  __syncthreads();
  float acc = bl2[j];
#pragma unroll
  for (int k = 0; k < 64; ++k)
    acc += wl2[j * 64 + k] * maS[k] + wr2[j * 64 + k] * mhS[k];
  m3S[j] = acc;
  __syncthreads();
  float c = cb1[j];
#pragma unroll
  for (int k = 0; k < 64; ++k) c += cw1[j * 64 + k] * m3S[k];
  tS[j] = fmaxf(c, 0.f);
  __syncthreads();
  float r = tS[j] * cw2[j];
#pragma unroll
  for (int off = 32; off > 0; off >>= 1) r += __shfl_down(r, off);
  if (j == 0) out[0] = 1.0f / (1.0f + expf(-(r + cb2[0])));
}

// ---------------- host launcher ----------------

extern "C" void kernel_launch(void* const* d_in, const int* in_sizes, int n_in,
                              void* d_out, int out_size, void* d_ws, size_t ws_size,
                              hipStream_t stream) {
  const float* x   = (const float*)d_in[0];
  const int* ei    = (const int*)d_in[1];
  const float* wl0 = (const float*)d_in[2];
  const float* bl0 = (const float*)d_in[3];
  const float* wr0 = (const float*)d_in[4];
  const float* wl1 = (const float*)d_in[5];
  const float* bl1 = (const float*)d_in[6];
  const float* wr1 = (const float*)d_in[7];
  const float* wl2 = (const float*)d_in[8];
  const float* bl2 = (const float*)d_in[9];
  const float* wr2 = (const float*)d_in[10];
  const float* g0  = (const float*)d_in[11];
  const float* be0 = (const float*)d_in[12];
  const float* m0  = (const float*)d_in[13];
  const float* v0  = (const float*)d_in[14];
  const float* g1  = (const float*)d_in[15];
  const float* be1 = (const float*)d_in[16];
  const float* m1  = (const float*)d_in[17];
  const float* v1  = (const float*)d_in[18];
  const float* cw1 = (const float*)d_in[19];
  const float* cb1 = (const float*)d_in[20];
  const float* cw2 = (const float*)d_in[21];
  const float* cb2 = (const float*)d_in[22];

  const int* srcp = ei;            // edge_index[0]
  const int* dstp = ei + N_EDGES;  // edge_index[1]

  char* ws = (char*)d_ws;
  size_t off = 0;
  auto alloc = [&](size_t bytes) {
    void* p = ws + off;
    off = align256(off + bytes);
    return p;
  };
  int* gfillD      = (int*)alloc((size_t)512 * 16 * 4);   // padded counters (64B apart)
  int* gfillS      = (int*)alloc((size_t)512 * 16 * 4);
  int* bbase       = (int*)alloc((size_t)512 * 4);
  unsigned* pairsD = (unsigned*)alloc((size_t)NB * CAP * 4);  // ~8 MB
  unsigned* pairsS = (unsigned*)alloc((size_t)NB * CAP * 4);  // ~8 MB
  int* rowptr      = (int*)alloc((size_t)N_NODES * 4);
  int* cnt         = (int*)alloc((size_t)N_NODES * 4);
  float* invdeg    = (float*)alloc((size_t)N_NODES * 4);
  float* coef      = (float*)alloc((size_t)N_NODES * 4);
  int* col         = (int*)alloc((size_t)N_EDGES * 4);
  float* sums      = (float*)alloc(128 * 4);
  unsigned char* h0 = (unsigned char*)alloc((size_t)N_NODES * 64);
  unsigned char* h1 = (unsigned char*)alloc((size_t)N_NODES * 64);
  (void)off; (void)ws_size; (void)in_sizes; (void)n_in; (void)out_size;

  hipMemsetAsync(gfillD, 0, (size_t)512 * 16 * 4, stream);
  hipMemsetAsync(gfillS, 0, (size_t)512 * 16 * 4, stream);
  hipMemsetAsync(sums, 0, 128 * 4, stream);

  partition_kernel<<<PB, PT, 0, stream>>>(x, h0, srcp, dstp,
                                          gfillD, gfillS, pairsD, pairsS);
  bscan_kernel<<<1, 512, 0, stream>>>(gfillD, bbase);
  csr_kernel<<<NB, 256, 0, stream>>>(pairsD, gfillD, bbase, col, rowptr, cnt, invdeg);
  coef_kernel<<<NB, 256, 0, stream>>>(pairsS, gfillS, invdeg, coef);

  layer_kernel<true, false><<<782, 512, 0, stream>>>(
      h0, rowptr, cnt, col, wl0, bl0, wr0, g0, be0, m0, v0, h1, nullptr, nullptr);
  layer_kernel<false, true><<<782, 512, 0, stream>>>(
      h1, rowptr, cnt, col, wl1, bl1, wr1, g1, be1, m1, v1, nullptr, coef, sums);
  final_kernel<<<1, 64, 0, stream>>>(sums, wl2, bl2, wr2, cw1, cb1, cw2, cb2,
                                     (float*)d_out);
}

// Round 11
// 185.767 us; speedup vs baseline: 1.7465x; 1.0168x over previous
//
#include <hip/hip_runtime.h>
#include <math.h>

#define N_NODES 100000
#define N_EDGES 1600000

static inline size_t align256(size_t x) { return (x + 255) & ~((size_t)255); }

constexpr int NB = (N_NODES + 255) / 256;  // 391 buckets (node>>8)
constexpr int CAP = 5120;                  // bucket capacity (avg 4092, max ~4400)
constexpr int PB = 512;                    // partition blocks
constexpr int PT = 512;                    // partition threads
constexpr int PCHUNK = N_EDGES / PB;       // 3125 (exact)

typedef _Float16 h2 __attribute__((ext_vector_type(2)));
typedef float f32x2 __attribute__((ext_vector_type(2)));
union HU { float f; unsigned u; h2 h; };

#if __has_builtin(__builtin_amdgcn_fdot2)
__device__ inline float fdot2f(h2 a, h2 b, float c) {
  return __builtin_amdgcn_fdot2(a, b, c, false);
}
#else
__device__ inline float fdot2f(h2 a, h2 b, float c) {
  return c + (float)a.x * (float)b.x + (float)a.y * (float)b.y;
}
#endif

#if __has_builtin(__builtin_amdgcn_cvt_pk_f32_fp8) && __has_builtin(__builtin_amdgcn_cvt_pk_fp8_f32)
#define FP8_HW 1
#else
#include <hip/hip_fp8.h>
#endif

// decode 4 fp8 (one u32) -> two f32x2   (u == 0 decodes to zeros)
__device__ inline void dec4(unsigned u, f32x2& lo, f32x2& hi) {
#ifdef FP8_HW
  lo = __builtin_amdgcn_cvt_pk_f32_fp8((int)u, false);
  hi = __builtin_amdgcn_cvt_pk_f32_fp8((int)u, true);
#else
  __hip_fp8_e4m3 v0, v1, v2, v3;
  v0.__x = u & 0xFF; v1.__x = (u >> 8) & 0xFF;
  v2.__x = (u >> 16) & 0xFF; v3.__x = (u >> 24) & 0xFF;
  lo.x = (float)v0; lo.y = (float)v1; hi.x = (float)v2; hi.y = (float)v3;
#endif
}

__device__ inline unsigned enc4(float a, float b, float c, float d) {
#ifdef FP8_HW
  int w = __builtin_amdgcn_cvt_pk_fp8_f32(a, b, 0, false);
  w = __builtin_amdgcn_cvt_pk_fp8_f32(c, d, w, true);
  return (unsigned)w;
#else
  return (unsigned)__hip_fp8_e4m3(a).__x | ((unsigned)__hip_fp8_e4m3(b).__x << 8) |
         ((unsigned)__hip_fp8_e4m3(c).__x << 16) | ((unsigned)__hip_fp8_e4m3(d).__x << 24);
#endif
}

__device__ inline unsigned char enc1(float a) {
#ifdef FP8_HW
  return (unsigned char)(__builtin_amdgcn_cvt_pk_fp8_f32(a, a, 0, false) & 0xFF);
#else
  return (unsigned char)__hip_fp8_e4m3(a).__x;
#endif
}

// ---------------- K1: dual partition, edges read from global ONCE ----------------
// raw (src,dst) staged in LDS; both D- and S-passes sort from LDS. Global
// atomics: 2*391 per block. Packed 4B entries; bucket runs written contiguously.
// Fused x -> fp8 convert at the end.

__global__ __launch_bounds__(PT) void partition_kernel(
    const float* __restrict__ x, unsigned char* __restrict__ h0,
    const int* __restrict__ src, const int* __restrict__ dst,
    int* __restrict__ gfillD, int* __restrict__ gfillS,
    unsigned* __restrict__ pairsD, unsigned* __restrict__ pairsS) {
  __shared__ int2 raw[PCHUNK];            // 25.0 KB
  __shared__ unsigned ents[PCHUNK];       // 12.5 KB
  __shared__ unsigned short bkt[PCHUNK];  //  6.3 KB
  __shared__ int hist[NB], lfill[NB], delta[NB];
  __shared__ int sc[PT];

  const int blk = blockIdx.x, t = threadIdx.x;
  const int e0 = blk * PCHUNK;

  for (int i = t; i < PCHUNK; i += PT) raw[i] = make_int2(src[e0 + i], dst[e0 + i]);
  __syncthreads();

#pragma unroll
  for (int pass = 0; pass < 2; ++pass) {
    int* gfill = pass ? gfillS : gfillD;
    unsigned* out = pass ? pairsS : pairsD;

    for (int i = t; i < NB; i += PT) hist[i] = 0;
    __syncthreads();
    for (int i = t; i < PCHUNK; i += PT) {
      int2 e = raw[i];
      int k = pass ? e.x : e.y;
      atomicAdd(&hist[k >> 8], 1);
    }
    __syncthreads();
    int v = (t < NB) ? hist[t] : 0;
    sc[t] = v;
    __syncthreads();
    for (int off = 1; off < PT; off <<= 1) {
      int a = (t >= off) ? sc[t - off] : 0;
      __syncthreads();
      sc[t] += a;
      __syncthreads();
    }
    if (t < NB) {
      int excl = sc[t] - v;
      lfill[t] = excl;
      int gb = atomicAdd(&gfill[t * 16], v);
      delta[t] = t * CAP + gb - excl;
    }
    __syncthreads();
    for (int i = t; i < PCHUNK; i += PT) {
      int2 e = raw[i];
      int k = pass ? e.x : e.y;
      int w = pass ? e.y : e.x;
      int b = k >> 8;
      int p = atomicAdd(&lfill[b], 1);
      ents[p] = (unsigned)w | ((unsigned)(k & 255) << 17);
      bkt[p] = (unsigned short)b;
    }
    __syncthreads();
    for (int i = t; i < PCHUNK; i += PT) out[delta[bkt[i]] + i] = ents[i];
    __syncthreads();
  }

  // fused x -> fp8 convert (grid-stride)
  const int gtid = blk * PT + t;
  const int nth = gridDim.x * PT;
  for (int i = gtid; i < N_NODES * 8; i += nth) {
    float4 a = ((const float4*)x)[2 * i];
    float4 b = ((const float4*)x)[2 * i + 1];
    ((uint2*)h0)[i] = make_uint2(enc4(a.x, a.y, a.z, a.w), enc4(b.x, b.y, b.z, b.w));
  }
}

// ---------------- K2: per-dst-bucket LDS counting sort -> col (padded), rowptr, cnt, invdeg ----
// col layout is per-bucket padded: node's edges live at rowptr[node] in [b*CAP, b*CAP+count).
// entry = src | (dst&255)<<17

__global__ __launch_bounds__(256) void csr_kernel(const unsigned* __restrict__ pairs,
                                                  const int* __restrict__ bfill,
                                                  int* __restrict__ col,
                                                  int* __restrict__ rowptr,
                                                  int* __restrict__ cnt,
                                                  float* __restrict__ invdeg) {
  __shared__ int hist[256], sc[256], offs[256];
  const int b = blockIdx.x;
  const int t = threadIdx.x;
  hist[t] = 0;
  __syncthreads();
  const int count = bfill[b * 16];
  const int base = b * CAP;
  const unsigned* bp = pairs + (size_t)b * CAP;
  for (int i = t; i < count; i += 256) atomicAdd(&hist[(bp[i] >> 17) & 255], 1);
  __syncthreads();
  int v = hist[t];
  sc[t] = v;
  __syncthreads();
  for (int off = 1; off < 256; off <<= 1) {
    int a = (t >= off) ? sc[t - off] : 0;
    __syncthreads();
    sc[t] += a;
    __syncthreads();
  }
  const int excl = sc[t] - v;
  offs[t] = base + excl;
  const int node = b * 256 + t;
  if (node < N_NODES) {
    rowptr[node] = base + excl;
    cnt[node] = v;
    invdeg[node] = 1.0f / (float)((v > 0) ? v : 1);
  }
  __syncthreads();
  for (int i = t; i < count; i += 256) {
    unsigned e = bp[i];
    int p = atomicAdd(&offs[(e >> 17) & 255], 1);
    col[p] = (int)(e & 0x1FFFF);
  }
}

// ---------------- K3: coef via per-src-bucket LDS accumulation ----------------
// entry = dst | (src&255)<<17 ; coef[s] = sum invdeg[dst] over out-edges.

__global__ __launch_bounds__(256) void coef_kernel(const unsigned* __restrict__ pairsS,
                                                   const int* __restrict__ gfillS,
                                                   const float* __restrict__ invdeg,
                                                   float* __restrict__ coef) {
  __shared__ float cl[256];
  const int b = blockIdx.x;
  const int t = threadIdx.x;
  cl[t] = 0.0f;
  __syncthreads();
  const int count = gfillS[b * 16];
  const unsigned* bp = pairsS + (size_t)b * CAP;
  for (int i = t; i < count; i += 256) {
    unsigned e = bp[i];
    atomicAdd(&cl[(e >> 17) & 255], invdeg[e & 0x1FFFF]);
  }
  __syncthreads();
  const int node = b * 256 + t;
  if (node < N_NODES) coef[node] = cl[t];
}

// ---------------- fused SAGEConv + BN + ReLU (layers 0 and 1), fp8 h ----------------
// block = 512 = 8 waves; each wave does ONE round of 8 nodes (grid 1563 ->
// 12504 waves ~ 12500 rounds; block-queue pipelining keeps 4 blocks/CU busy).
// Gather: mask-padded batches of 8 clamped loads -> no serial remainder loop.

template <bool WRITE_OUT, bool DO_SUMS>
__global__ __launch_bounds__(512) void layer_kernel(
    const unsigned char* __restrict__ hin, const int* __restrict__ rowptr,
    const int* __restrict__ cnt, const int* __restrict__ col,
    const float* __restrict__ wl, const float* __restrict__ bl,
    const float* __restrict__ wr,
    const float* __restrict__ g, const float* __restrict__ be,
    const float* __restrict__ m, const float* __restrict__ v,
    unsigned char* __restrict__ hout, const float* __restrict__ coef,
    float* __restrict__ sums) {
  __shared__ uint4 wwS[1024];        // [k4*64+j]: {wl01,wl23,wr01,wr23} fp16 pairs, 16 KB
  __shared__ uint4 exS[8][8][17];    // [wave][node][k4(16)+pad]
  __shared__ float scaleS[64], shiftS[64], biasS[64];
  __shared__ float redS[8][128];

  const int tid = threadIdx.x;

  for (int idx = tid; idx < 1024; idx += 512) {
    int k4 = idx >> 6, j = idx & 63;
    const float* pl = wl + j * 64 + k4 * 4;
    const float* pr = wr + j * 64 + k4 * 4;
    HU a0, a1, o0, o1;
    a0.h.x = (_Float16)pl[0]; a0.h.y = (_Float16)pl[1];
    a1.h.x = (_Float16)pl[2]; a1.h.y = (_Float16)pl[3];
    o0.h.x = (_Float16)pr[0]; o0.h.y = (_Float16)pr[1];
    o1.h.x = (_Float16)pr[2]; o1.h.y = (_Float16)pr[3];
    wwS[idx] = make_uint4(a0.u, a1.u, o0.u, o1.u);
  }
  if (tid < 64) {
    float sc = rsqrtf(v[tid] + 1e-5f) * g[tid];
    scaleS[tid] = sc;
    shiftS[tid] = be[tid] - m[tid] * sc;
    biasS[tid] = bl[tid];
  }
  __syncthreads();

  const int lane = tid & 63;
  const int wv = tid >> 6;
  const int slot = lane >> 3;   // 0..7 node slot
  const int c = lane & 7;       // channel octet (8 fp8 = 8 B)
  const int wid = blockIdx.x * 8 + wv;
  const int nwaves = gridDim.x * 8;
  const uint2* __restrict__ hrows = (const uint2*)hin;  // 8 uint2 per 64B row
  float accsum = 0.0f, accsum2 = 0.0f;

  for (int gidx = wid; gidx < (N_NODES / 8); gidx += nwaves) {
    const int nbase = gidx * 8;

    // ---- phase 1: gather 8 nodes concurrently, mask-padded batches of 8 ----
    {
      const int node = nbase + slot;
      const uint2 uo = hrows[node * 8 + c];
      const int start = rowptr[node];
      const int deg = cnt[node];
      const int* cp = col + start;
      f32x2 a01 = {0.f, 0.f}, a23 = {0.f, 0.f}, a45 = {0.f, 0.f}, a67 = {0.f, 0.f};
      for (int e = 0; e < deg; e += 8) {
        uint2 u[8];
#pragma unroll
        for (int i = 0; i < 8; ++i) {
          int idx = (e + i < deg) ? (e + i) : (deg - 1);  // clamped, always safe
          u[i] = hrows[cp[idx] * 8 + c];
        }
#pragma unroll
        for (int i = 0; i < 8; ++i) {
          const bool valid = (e + i) < deg;
          unsigned ux = valid ? u[i].x : 0u;   // fp8 pattern 0 decodes to 0.0
          unsigned uy = valid ? u[i].y : 0u;
          f32x2 lo, hi;
          dec4(ux, lo, hi); a01 += lo; a23 += hi;
          dec4(uy, lo, hi); a45 += lo; a67 += hi;
        }
      }
      const float inv = (deg > 0) ? (1.0f / (float)deg) : 0.0f;
      a01 *= inv; a23 *= inv; a45 *= inv; a67 *= inv;
      f32x2 olo, ohi;
      HU wa0, wa1, wo0, wo1;
      // channels 8c..8c+3 -> k4 = 2c
      dec4(uo.x, olo, ohi);
      wa0.h.x = (_Float16)a01.x; wa0.h.y = (_Float16)a01.y;
      wa1.h.x = (_Float16)a23.x; wa1.h.y = (_Float16)a23.y;
      wo0.h.x = (_Float16)olo.x; wo0.h.y = (_Float16)olo.y;
      wo1.h.x = (_Float16)ohi.x; wo1.h.y = (_Float16)ohi.y;
      exS[wv][slot][2 * c] = make_uint4(wa0.u, wa1.u, wo0.u, wo1.u);
      // channels 8c+4..8c+7 -> k4 = 2c+1
      dec4(uo.y, olo, ohi);
      wa0.h.x = (_Float16)a45.x; wa0.h.y = (_Float16)a45.y;
      wa1.h.x = (_Float16)a67.x; wa1.h.y = (_Float16)a67.y;
      wo0.h.x = (_Float16)olo.x; wo0.h.y = (_Float16)olo.y;
      wo1.h.x = (_Float16)ohi.x; wo1.h.y = (_Float16)ohi.y;
      exS[wv][slot][2 * c + 1] = make_uint4(wa0.u, wa1.u, wo0.u, wo1.u);
    }
    // same-wave produce/consume; compiler inserts lgkmcnt waits -- no barrier

    // ---- phase 2: transform, lane = output channel j ----
    float out[8] = {0.f, 0.f, 0.f, 0.f, 0.f, 0.f, 0.f, 0.f};
#pragma unroll 4
    for (int k4 = 0; k4 < 16; ++k4) {
      uint4 w4 = wwS[k4 * 64 + lane];
      HU wl01, wl23, wr01, wr23;
      wl01.u = w4.x; wl23.u = w4.y; wr01.u = w4.z; wr23.u = w4.w;
#pragma unroll
      for (int n = 0; n < 8; ++n) {
        uint4 ao = exS[wv][n][k4];
        HU a01, a23, o01, o23;
        a01.u = ao.x; a23.u = ao.y; o01.u = ao.z; o23.u = ao.w;
        float t = out[n];
        t = fdot2f(a01.h, wl01.h, t);
        t = fdot2f(a23.h, wl23.h, t);
        t = fdot2f(o01.h, wr01.h, t);
        t = fdot2f(o23.h, wr23.h, t);
        out[n] = t;
      }
    }

    const float sc = scaleS[lane], sh = shiftS[lane], bi = biasS[lane];
#pragma unroll
    for (int n = 0; n < 8; ++n) {
      float o = fmaxf((out[n] + bi) * sc + sh, 0.0f);
      if (DO_SUMS) {
        accsum += o;
        accsum2 += coef[nbase + n] * o;
      }
      if (WRITE_OUT) hout[(size_t)(nbase + n) * 64 + lane] = enc1(o);
    }
  }

  if (DO_SUMS) {
    redS[wv][lane] = accsum;
    redS[wv][64 + lane] = accsum2;
    __syncthreads();
    if (wv == 0) {
      float t0 = 0.f, t1 = 0.f;
#pragma unroll
      for (int w = 0; w < 8; ++w) {
        t0 += redS[w][lane];
        t1 += redS[w][64 + lane];
      }
      atomicAdd(&sums[lane], t0);
      atomicAdd(&sums[64 + lane], t1);
    }
  }
}

// ---------------- collapsed layer 2 + classifier + sigmoid ----------------

__global__ void final_kernel(const float* __restrict__ sums,
                             const float* __restrict__ wl2, const float* __restrict__ bl2,
                             const float* __restrict__ wr2,
                             const float* __restrict__ cw1, const float* __restrict__ cb1,
                             const float* __restrict__ cw2, const float* __restrict__ cb2,
                             float* __restrict__ out) {
  __shared__ float maS[64], mhS[64], m3S[64], tS[64];
  int j = threadIdx.x;  // 64 threads
  float invN = 1.0f / (float)N_NODES;
  mhS[j] = sums[j] * invN;        // mean of h2
  maS[j] = sums[64 + j] * invN;   // mean of aggr3
  __syncthreads();
  float acc = bl2[j];
#pragma unroll
  for (int k = 0; k < 64; ++k)
    acc += wl2[j * 64 + k] * maS[k] + wr2[j * 64 + k] * mhS[k];
  m3S[j] = acc;
  __syncthreads();
  float c = cb1[j];
#pragma unroll
  for (int k = 0; k < 64; ++k) c += cw1[j * 64 + k] * m3S[k];
  tS[j] = fmaxf(c, 0.f);
  __syncthreads();
  float r = tS[j] * cw2[j];
#pragma unroll
  for (int off = 32; off > 0; off >>= 1) r += __shfl_down(r, off);
  if (j == 0) out[0] = 1.0f / (1.0f + expf(-(r + cb2[0])));
}

// ---------------- host launcher ----------------

extern "C" void kernel_launch(void* const* d_in, const int* in_sizes, int n_in,
                              void* d_out, int out_size, void* d_ws, size_t ws_size,
                              hipStream_t stream) {
  const float* x   = (const float*)d_in[0];
  const int* ei    = (const int*)d_in[1];
  const float* wl0 = (const float*)d_in[2];
  const float* bl0 = (const float*)d_in[3];
  const float* wr0 = (const float*)d_in[4];
  const float* wl1 = (const float*)d_in[5];
  const float* bl1 = (const float*)d_in[6];
  const float* wr1 = (const float*)d_in[7];
  const float* wl2 = (const float*)d_in[8];
  const float* bl2 = (const float*)d_in[9];
  const float* wr2 = (const float*)d_in[10];
  const float* g0  = (const float*)d_in[11];
  const float* be0 = (const float*)d_in[12];
  const float* m0  = (const float*)d_in[13];
  const float* v0  = (const float*)d_in[14];
  const float* g1  = (const float*)d_in[15];
  const float* be1 = (const float*)d_in[16];
  const float* m1  = (const float*)d_in[17];
  const float* v1  = (const float*)d_in[18];
  const float* cw1 = (const float*)d_in[19];
  const float* cb1 = (const float*)d_in[20];
  const float* cw2 = (const float*)d_in[21];
  const float* cb2 = (const float*)d_in[22];

  const int* srcp = ei;            // edge_index[0]
  const int* dstp = ei + N_EDGES;  // edge_index[1]

  char* ws = (char*)d_ws;
  size_t off = 0;
  auto alloc = [&](size_t bytes) {
    void* p = ws + off;
    off = align256(off + bytes);
    return p;
  };
  int* gfillD      = (int*)alloc((size_t)512 * 16 * 4);   // padded counters (64B apart)
  int* gfillS      = (int*)alloc((size_t)512 * 16 * 4);
  unsigned* pairsD = (unsigned*)alloc((size_t)NB * CAP * 4);  // ~8 MB
  unsigned* pairsS = (unsigned*)alloc((size_t)NB * CAP * 4);  // ~8 MB
  int* rowptr      = (int*)alloc((size_t)N_NODES * 4);
  int* cnt         = (int*)alloc((size_t)N_NODES * 4);
  float* invdeg    = (float*)alloc((size_t)N_NODES * 4);
  float* coef      = (float*)alloc((size_t)N_NODES * 4);
  int* col         = (int*)alloc((size_t)NB * CAP * 4);       // padded per bucket, ~8 MB
  float* sums      = (float*)alloc(128 * 4);
  unsigned char* h0 = (unsigned char*)alloc((size_t)N_NODES * 64);
  unsigned char* h1 = (unsigned char*)alloc((size_t)N_NODES * 64);
  (void)off; (void)ws_size; (void)in_sizes; (void)n_in; (void)out_size;

  hipMemsetAsync(gfillD, 0, (size_t)512 * 16 * 4, stream);
  hipMemsetAsync(gfillS, 0, (size_t)512 * 16 * 4, stream);
  hipMemsetAsync(sums, 0, 128 * 4, stream);

  partition_kernel<<<PB, PT, 0, stream>>>(x, h0, srcp, dstp,
                                          gfillD, gfillS, pairsD, pairsS);
  csr_kernel<<<NB, 256, 0, stream>>>(pairsD, gfillD, col, rowptr, cnt, invdeg);
  coef_kernel<<<NB, 256, 0, stream>>>(pairsS, gfillS, invdeg, coef);

  layer_kernel<true, false><<<1563, 512, 0, stream>>>(
      h0, rowptr, cnt, col, wl0, bl0, wr0, g0, be0, m0, v0, h1, nullptr, nullptr);
  layer_kernel<false, true><<<1563, 512, 0, stream>>>(
      h1, rowptr, cnt, col, wl1, bl1, wr1, g1, be1, m1, v1, nullptr, coef, sums);
  final_kernel<<<1, 64, 0, stream>>>(sums, wl2, bl2, wr2, cw1, cb1, cw2, cb2,
                                     (float*)d_out);
}

// Round 12
// 185.670 us; speedup vs baseline: 1.7474x; 1.0005x over previous
//
#include <hip/hip_runtime.h>
#include <math.h>

#define N_NODES 100000
#define N_EDGES 1600000

static inline size_t align256(size_t x) { return (x + 255) & ~((size_t)255); }

constexpr int NB = (N_NODES + 255) / 256;  // 391 buckets (node>>8)
constexpr int CAP = 5120;                  // bucket capacity (avg 4092, max ~4400)
constexpr int PB = 512;                    // partition blocks
constexpr int PT = 512;                    // partition threads
constexpr int PCHUNK = N_EDGES / PB;       // 3125 (exact)
constexpr int NOCT = N_NODES / 8;          // 12500 node-octets

typedef _Float16 h2 __attribute__((ext_vector_type(2)));
typedef float f32x2 __attribute__((ext_vector_type(2)));
union HU { float f; unsigned u; h2 h; };

#if __has_builtin(__builtin_amdgcn_fdot2)
__device__ inline float fdot2f(h2 a, h2 b, float c) {
  return __builtin_amdgcn_fdot2(a, b, c, false);
}
#else
__device__ inline float fdot2f(h2 a, h2 b, float c) {
  return c + (float)a.x * (float)b.x + (float)a.y * (float)b.y;
}
#endif

#if __has_builtin(__builtin_amdgcn_cvt_pk_f32_fp8) && __has_builtin(__builtin_amdgcn_cvt_pk_fp8_f32)
#define FP8_HW 1
#else
#include <hip/hip_fp8.h>
#endif

// decode 4 fp8 (one u32) -> two f32x2   (u == 0 decodes to zeros)
__device__ inline void dec4(unsigned u, f32x2& lo, f32x2& hi) {
#ifdef FP8_HW
  lo = __builtin_amdgcn_cvt_pk_f32_fp8((int)u, false);
  hi = __builtin_amdgcn_cvt_pk_f32_fp8((int)u, true);
#else
  __hip_fp8_e4m3 v0, v1, v2, v3;
  v0.__x = u & 0xFF; v1.__x = (u >> 8) & 0xFF;
  v2.__x = (u >> 16) & 0xFF; v3.__x = (u >> 24) & 0xFF;
  lo.x = (float)v0; lo.y = (float)v1; hi.x = (float)v2; hi.y = (float)v3;
#endif
}

__device__ inline unsigned enc4(float a, float b, float c, float d) {
#ifdef FP8_HW
  int w = __builtin_amdgcn_cvt_pk_fp8_f32(a, b, 0, false);
  w = __builtin_amdgcn_cvt_pk_fp8_f32(c, d, w, true);
  return (unsigned)w;
#else
  return (unsigned)__hip_fp8_e4m3(a).__x | ((unsigned)__hip_fp8_e4m3(b).__x << 8) |
         ((unsigned)__hip_fp8_e4m3(c).__x << 16) | ((unsigned)__hip_fp8_e4m3(d).__x << 24);
#endif
}

__device__ inline unsigned char enc1(float a) {
#ifdef FP8_HW
  return (unsigned char)(__builtin_amdgcn_cvt_pk_fp8_f32(a, a, 0, false) & 0xFF);
#else
  return (unsigned char)__hip_fp8_e4m3(a).__x;
#endif
}

// ---------------- K1: dual partition, edges read from global ONCE ----------------

__global__ __launch_bounds__(PT) void partition_kernel(
    const float* __restrict__ x, unsigned char* __restrict__ h0,
    const int* __restrict__ src, const int* __restrict__ dst,
    int* __restrict__ gfillD, int* __restrict__ gfillS,
    unsigned* __restrict__ pairsD, unsigned* __restrict__ pairsS) {
  __shared__ int2 raw[PCHUNK];            // 25.0 KB
  __shared__ unsigned ents[PCHUNK];       // 12.5 KB
  __shared__ unsigned short bkt[PCHUNK];  //  6.3 KB
  __shared__ int hist[NB], lfill[NB], delta[NB];
  __shared__ int sc[PT];

  const int blk = blockIdx.x, t = threadIdx.x;
  const int e0 = blk * PCHUNK;

  for (int i = t; i < PCHUNK; i += PT) raw[i] = make_int2(src[e0 + i], dst[e0 + i]);
  __syncthreads();

#pragma unroll
  for (int pass = 0; pass < 2; ++pass) {
    int* gfill = pass ? gfillS : gfillD;
    unsigned* out = pass ? pairsS : pairsD;

    for (int i = t; i < NB; i += PT) hist[i] = 0;
    __syncthreads();
    for (int i = t; i < PCHUNK; i += PT) {
      int2 e = raw[i];
      int k = pass ? e.x : e.y;
      atomicAdd(&hist[k >> 8], 1);
    }
    __syncthreads();
    int v = (t < NB) ? hist[t] : 0;
    sc[t] = v;
    __syncthreads();
    for (int off = 1; off < PT; off <<= 1) {
      int a = (t >= off) ? sc[t - off] : 0;
      __syncthreads();
      sc[t] += a;
      __syncthreads();
    }
    if (t < NB) {
      int excl = sc[t] - v;
      lfill[t] = excl;
      int gb = atomicAdd(&gfill[t * 16], v);
      delta[t] = t * CAP + gb - excl;
    }
    __syncthreads();
    for (int i = t; i < PCHUNK; i += PT) {
      int2 e = raw[i];
      int k = pass ? e.x : e.y;
      int w = pass ? e.y : e.x;
      int b = k >> 8;
      int p = atomicAdd(&lfill[b], 1);
      ents[p] = (unsigned)w | ((unsigned)(k & 255) << 17);
      bkt[p] = (unsigned short)b;
    }
    __syncthreads();
    for (int i = t; i < PCHUNK; i += PT) out[delta[bkt[i]] + i] = ents[i];
    __syncthreads();
  }

  // fused x -> fp8 convert (grid-stride)
  const int gtid = blk * PT + t;
  const int nth = gridDim.x * PT;
  for (int i = gtid; i < N_NODES * 8; i += nth) {
    float4 a = ((const float4*)x)[2 * i];
    float4 b = ((const float4*)x)[2 * i + 1];
    ((uint2*)h0)[i] = make_uint2(enc4(a.x, a.y, a.z, a.w), enc4(b.x, b.y, b.z, b.w));
  }
}

// ---------------- K2: per-dst-bucket LDS counting sort -> col (padded), rowptr, cnt, invdeg ----

__global__ __launch_bounds__(256) void csr_kernel(const unsigned* __restrict__ pairs,
                                                  const int* __restrict__ bfill,
                                                  int* __restrict__ col,
                                                  int* __restrict__ rowptr,
                                                  int* __restrict__ cnt,
                                                  float* __restrict__ invdeg) {
  __shared__ int hist[256], sc[256], offs[256];
  const int b = blockIdx.x;
  const int t = threadIdx.x;
  hist[t] = 0;
  __syncthreads();
  const int count = bfill[b * 16];
  const int base = b * CAP;
  const unsigned* bp = pairs + (size_t)b * CAP;
  for (int i = t; i < count; i += 256) atomicAdd(&hist[(bp[i] >> 17) & 255], 1);
  __syncthreads();
  int v = hist[t];
  sc[t] = v;
  __syncthreads();
  for (int off = 1; off < 256; off <<= 1) {
    int a = (t >= off) ? sc[t - off] : 0;
    __syncthreads();
    sc[t] += a;
    __syncthreads();
  }
  const int excl = sc[t] - v;
  offs[t] = base + excl;
  const int node = b * 256 + t;
  if (node < N_NODES) {
    rowptr[node] = base + excl;
    cnt[node] = v;
    invdeg[node] = 1.0f / (float)((v > 0) ? v : 1);
  }
  __syncthreads();
  for (int i = t; i < count; i += 256) {
    unsigned e = bp[i];
    int p = atomicAdd(&offs[(e >> 17) & 255], 1);
    col[p] = (int)(e & 0x1FFFF);
  }
}

// ---------------- K3: coef via per-src-bucket LDS accumulation ----------------

__global__ __launch_bounds__(256) void coef_kernel(const unsigned* __restrict__ pairsS,
                                                   const int* __restrict__ gfillS,
                                                   const float* __restrict__ invdeg,
                                                   float* __restrict__ coef) {
  __shared__ float cl[256];
  const int b = blockIdx.x;
  const int t = threadIdx.x;
  cl[t] = 0.0f;
  __syncthreads();
  const int count = gfillS[b * 16];
  const unsigned* bp = pairsS + (size_t)b * CAP;
  for (int i = t; i < count; i += 256) {
    unsigned e = bp[i];
    atomicAdd(&cl[(e >> 17) & 255], invdeg[e & 0x1FFFF]);
  }
  __syncthreads();
  const int node = b * 256 + t;
  if (node < N_NODES) coef[node] = cl[t];
}

// ---------------- K4: gather/mean (latency-critical, ZERO LDS, no barriers) ----------------
// 8-lane group per node; 8 nodes per wave; 16-deep clamped+masked batches;
// grid-stride. Writes aggr as fp16 (uint4 per lane = 8 channels, 128B/node).

__global__ __launch_bounds__(256) void gather_kernel(
    const unsigned char* __restrict__ hin, const int* __restrict__ rowptr,
    const int* __restrict__ cnt, const int* __restrict__ col,
    uint4* __restrict__ aggr) {
  const int tid = threadIdx.x;
  const int lane = tid & 63;
  const int wv = tid >> 6;
  const int slot = lane >> 3;   // 0..7
  const int c = lane & 7;       // channel octet
  const int wid = blockIdx.x * 4 + wv;
  const int nwaves = gridDim.x * 4;
  const uint2* __restrict__ hrows = (const uint2*)hin;

  for (int oct = wid; oct < NOCT; oct += nwaves) {
    const int node = oct * 8 + slot;
    const int deg = cnt[node];
    const int* cp = col + rowptr[node];
    f32x2 a01 = {0.f, 0.f}, a23 = {0.f, 0.f}, a45 = {0.f, 0.f}, a67 = {0.f, 0.f};
    for (int e = 0; e < deg; e += 16) {
      uint2 u[16];
#pragma unroll
      for (int i = 0; i < 16; ++i) {
        int idx = (e + i < deg) ? (e + i) : (deg - 1);  // clamped, always safe
        u[i] = hrows[cp[idx] * 8 + c];
      }
#pragma unroll
      for (int i = 0; i < 16; ++i) {
        const bool valid = (e + i) < deg;
        unsigned ux = valid ? u[i].x : 0u;
        unsigned uy = valid ? u[i].y : 0u;
        f32x2 lo, hi;
        dec4(ux, lo, hi); a01 += lo; a23 += hi;
        dec4(uy, lo, hi); a45 += lo; a67 += hi;
      }
    }
    const float inv = (deg > 0) ? (1.0f / (float)deg) : 0.0f;
    a01 *= inv; a23 *= inv; a45 *= inv; a67 *= inv;
    HU w0, w1, w2, w3;
    w0.h.x = (_Float16)a01.x; w0.h.y = (_Float16)a01.y;
    w1.h.x = (_Float16)a23.x; w1.h.y = (_Float16)a23.y;
    w2.h.x = (_Float16)a45.x; w2.h.y = (_Float16)a45.y;
    w3.h.x = (_Float16)a67.x; w3.h.y = (_Float16)a67.y;
    aggr[(size_t)node * 8 + c] = make_uint4(w0.u, w1.u, w2.u, w3.u);
  }
}

// ---------------- K5: transform (streaming, coalesced) ----------------
// Reads own h (fp8) + aggr (fp16) coalesced, LDS exchange, dot2 transform,
// BN+ReLU. WRITE_OUT: store fp8 h. DO_SUMS: sums[j]=sum h[j], sums[64+j]=
// sum coef[n]*h[j] (collapsed layer 2; h2 never materialized).

template <bool WRITE_OUT, bool DO_SUMS>
__global__ __launch_bounds__(512) void transform_kernel(
    const unsigned char* __restrict__ hin, const uint4* __restrict__ aggr,
    const float* __restrict__ wl, const float* __restrict__ bl,
    const float* __restrict__ wr,
    const float* __restrict__ g, const float* __restrict__ be,
    const float* __restrict__ m, const float* __restrict__ v,
    unsigned char* __restrict__ hout, const float* __restrict__ coef,
    float* __restrict__ sums) {
  __shared__ uint4 wwS[1024];        // [k4*64+j]: {wl01,wl23,wr01,wr23} fp16 pairs, 16 KB
  __shared__ uint4 exS[8][8][17];    // [wave][node][k4(16)+pad]
  __shared__ float scaleS[64], shiftS[64], biasS[64];
  __shared__ float redS[8][128];

  const int tid = threadIdx.x;

  for (int idx = tid; idx < 1024; idx += 512) {
    int k4 = idx >> 6, j = idx & 63;
    const float* pl = wl + j * 64 + k4 * 4;
    const float* pr = wr + j * 64 + k4 * 4;
    HU a0, a1, o0, o1;
    a0.h.x = (_Float16)pl[0]; a0.h.y = (_Float16)pl[1];
    a1.h.x = (_Float16)pl[2]; a1.h.y = (_Float16)pl[3];
    o0.h.x = (_Float16)pr[0]; o0.h.y = (_Float16)pr[1];
    o1.h.x = (_Float16)pr[2]; o1.h.y = (_Float16)pr[3];
    wwS[idx] = make_uint4(a0.u, a1.u, o0.u, o1.u);
  }
  if (tid < 64) {
    float sc = rsqrtf(v[tid] + 1e-5f) * g[tid];
    scaleS[tid] = sc;
    shiftS[tid] = be[tid] - m[tid] * sc;
    biasS[tid] = bl[tid];
  }
  __syncthreads();

  const int lane = tid & 63;
  const int wv = tid >> 6;
  const int slot = lane >> 3;   // 0..7
  const int c = lane & 7;       // channel octet
  const int wid = blockIdx.x * 8 + wv;
  const int nwaves = gridDim.x * 8;
  const uint2* __restrict__ hrows = (const uint2*)hin;
  float accsum = 0.0f, accsum2 = 0.0f;

  for (int oct = wid; oct < NOCT; oct += nwaves) {
    const int nbase = oct * 8;
    const int node = nbase + slot;

    // coalesced: own row (fp8) + aggr row (fp16)
    const uint2 uo = hrows[node * 8 + c];
    const uint4 ag = aggr[(size_t)node * 8 + c];
    f32x2 olo, ohi;
    HU wo0, wo1;
    // channels 8c..8c+3 -> k4 = 2c
    dec4(uo.x, olo, ohi);
    wo0.h.x = (_Float16)olo.x; wo0.h.y = (_Float16)olo.y;
    wo1.h.x = (_Float16)ohi.x; wo1.h.y = (_Float16)ohi.y;
    exS[wv][slot][2 * c] = make_uint4(ag.x, ag.y, wo0.u, wo1.u);
    // channels 8c+4..8c+7 -> k4 = 2c+1
    dec4(uo.y, olo, ohi);
    wo0.h.x = (_Float16)olo.x; wo0.h.y = (_Float16)olo.y;
    wo1.h.x = (_Float16)ohi.x; wo1.h.y = (_Float16)ohi.y;
    exS[wv][slot][2 * c + 1] = make_uint4(ag.z, ag.w, wo0.u, wo1.u);
    // same-wave produce/consume; compiler inserts lgkmcnt waits -- no barrier

    float out[8] = {0.f, 0.f, 0.f, 0.f, 0.f, 0.f, 0.f, 0.f};
#pragma unroll 4
    for (int k4 = 0; k4 < 16; ++k4) {
      uint4 w4 = wwS[k4 * 64 + lane];
      HU wl01, wl23, wr01, wr23;
      wl01.u = w4.x; wl23.u = w4.y; wr01.u = w4.z; wr23.u = w4.w;
#pragma unroll
      for (int n = 0; n < 8; ++n) {
        uint4 ao = exS[wv][n][k4];
        HU a01, a23, o01, o23;
        a01.u = ao.x; a23.u = ao.y; o01.u = ao.z; o23.u = ao.w;
        float t = out[n];
        t = fdot2f(a01.h, wl01.h, t);
        t = fdot2f(a23.h, wl23.h, t);
        t = fdot2f(o01.h, wr01.h, t);
        t = fdot2f(o23.h, wr23.h, t);
        out[n] = t;
      }
    }

    const float sc = scaleS[lane], sh = shiftS[lane], bi = biasS[lane];
#pragma unroll
    for (int n = 0; n < 8; ++n) {
      float o = fmaxf((out[n] + bi) * sc + sh, 0.0f);
      if (DO_SUMS) {
        accsum += o;
        accsum2 += coef[nbase + n] * o;
      }
      if (WRITE_OUT) hout[(size_t)(nbase + n) * 64 + lane] = enc1(o);
    }
  }

  if (DO_SUMS) {
    redS[wv][lane] = accsum;
    redS[wv][64 + lane] = accsum2;
    __syncthreads();
    if (wv == 0) {
      float t0 = 0.f, t1 = 0.f;
#pragma unroll
      for (int w = 0; w < 8; ++w) {
        t0 += redS[w][lane];
        t1 += redS[w][64 + lane];
      }
      atomicAdd(&sums[lane], t0);
      atomicAdd(&sums[64 + lane], t1);
    }
  }
}

// ---------------- collapsed layer 2 + classifier + sigmoid ----------------

__global__ void final_kernel(const float* __restrict__ sums,
                             const float* __restrict__ wl2, const float* __restrict__ bl2,
                             const float* __restrict__ wr2,
                             const float* __restrict__ cw1, const float* __restrict__ cb1,
                             const float* __restrict__ cw2, const float* __restrict__ cb2,
                             float* __restrict__ out) {
  __shared__ float maS[64], mhS[64], m3S[64], tS[64];
  int j = threadIdx.x;  // 64 threads
  float invN = 1.0f / (float)N_NODES;
  mhS[j] = sums[j] * invN;        // mean of h2
  maS[j] = sums[64 + j] * invN;   // mean of aggr3
  __syncthreads();
  float acc = bl2[j];
#pragma unroll
  for (int k = 0; k < 64; ++k)
    acc += wl2[j * 64 + k] * maS[k] + wr2[j * 64 + k] * mhS[k];
  m3S[j] = acc;
  __syncthreads();
  float c = cb1[j];
#pragma unroll
  for (int k = 0; k < 64; ++k) c += cw1[j * 64 + k] * m3S[k];
  tS[j] = fmaxf(c, 0.f);
  __syncthreads();
  float r = tS[j] * cw2[j];
#pragma unroll
  for (int off = 32; off > 0; off >>= 1) r += __shfl_down(r, off);
  if (j == 0) out[0] = 1.0f / (1.0f + expf(-(r + cb2[0])));
}

// ---------------- host launcher ----------------

extern "C" void kernel_launch(void* const* d_in, const int* in_sizes, int n_in,
                              void* d_out, int out_size, void* d_ws, size_t ws_size,
                              hipStream_t stream) {
  const float* x   = (const float*)d_in[0];
  const int* ei    = (const int*)d_in[1];
  const float* wl0 = (const float*)d_in[2];
  const float* bl0 = (const float*)d_in[3];
  const float* wr0 = (const float*)d_in[4];
  const float* wl1 = (const float*)d_in[5];
  const float* bl1 = (const float*)d_in[6];
  const float* wr1 = (const float*)d_in[7];
  const float* wl2 = (const float*)d_in[8];
  const float* bl2 = (const float*)d_in[9];
  const float* wr2 = (const float*)d_in[10];
  const float* g0  = (const float*)d_in[11];
  const float* be0 = (const float*)d_in[12];
  const float* m0  = (const float*)d_in[13];
  const float* v0  = (const float*)d_in[14];
  const float* g1  = (const float*)d_in[15];
  const float* be1 = (const float*)d_in[16];
  const float* m1  = (const float*)d_in[17];
  const float* v1  = (const float*)d_in[18];
  const float* cw1 = (const float*)d_in[19];
  const float* cb1 = (const float*)d_in[20];
  const float* cw2 = (const float*)d_in[21];
  const float* cb2 = (const float*)d_in[22];

  const int* srcp = ei;            // edge_index[0]
  const int* dstp = ei + N_EDGES;  // edge_index[1]

  char* ws = (char*)d_ws;
  size_t off = 0;
  auto alloc = [&](size_t bytes) {
    void* p = ws + off;
    off = align256(off + bytes);
    return p;
  };
  int* gfillD      = (int*)alloc((size_t)512 * 16 * 4);   // padded counters (64B apart)
  int* gfillS      = (int*)alloc((size_t)512 * 16 * 4);
  unsigned* pairsD = (unsigned*)alloc((size_t)NB * CAP * 4);  // ~8 MB
  unsigned* pairsS = (unsigned*)alloc((size_t)NB * CAP * 4);  // ~8 MB
  int* rowptr      = (int*)alloc((size_t)N_NODES * 4);
  int* cnt         = (int*)alloc((size_t)N_NODES * 4);
  float* invdeg    = (float*)alloc((size_t)N_NODES * 4);
  float* coef      = (float*)alloc((size_t)N_NODES * 4);
  int* col         = (int*)alloc((size_t)NB * CAP * 4);       // padded per bucket, ~8 MB
  float* sums      = (float*)alloc(128 * 4);
  unsigned char* h0 = (unsigned char*)alloc((size_t)N_NODES * 64);
  unsigned char* h1 = (unsigned char*)alloc((size_t)N_NODES * 64);
  uint4* aggr      = (uint4*)alloc((size_t)N_NODES * 8 * 16);  // fp16 aggr, 12.8 MB
  (void)off; (void)ws_size; (void)in_sizes; (void)n_in; (void)out_size;

  hipMemsetAsync(gfillD, 0, (size_t)512 * 16 * 4, stream);
  hipMemsetAsync(gfillS, 0, (size_t)512 * 16 * 4, stream);
  hipMemsetAsync(sums, 0, 128 * 4, stream);

  partition_kernel<<<PB, PT, 0, stream>>>(x, h0, srcp, dstp,
                                          gfillD, gfillS, pairsD, pairsS);
  csr_kernel<<<NB, 256, 0, stream>>>(pairsD, gfillD, col, rowptr, cnt, invdeg);
  coef_kernel<<<NB, 256, 0, stream>>>(pairsS, gfillS, invdeg, coef);

  // layer 0
  gather_kernel<<<1024, 256, 0, stream>>>(h0, rowptr, cnt, col, aggr);
  transform_kernel<true, false><<<512, 512, 0, stream>>>(
      h0, aggr, wl0, bl0, wr0, g0, be0, m0, v0, h1, nullptr, nullptr);
  // layer 1 (+ collapsed layer 2 sums)
  gather_kernel<<<1024, 256, 0, stream>>>(h1, rowptr, cnt, col, aggr);
  transform_kernel<false, true><<<512, 512, 0, stream>>>(
      h1, aggr, wl1, bl1, wr1, g1, be1, m1, v1, nullptr, coef, sums);

  final_kernel<<<1, 64, 0, stream>>>(sums, wl2, bl2, wr2, cw1, cb1, cw2, cb2,
                                     (float*)d_out);
}